// Round 6
// baseline (18327.104 us; speedup 1.0000x reference)
//
#include <hip/hip_runtime.h>

#define DEV static __device__ __forceinline__

typedef short  s16x8 __attribute__((ext_vector_type(8)));
typedef float  f32x4 __attribute__((ext_vector_type(4)));
typedef _Float16 h2f __attribute__((ext_vector_type(2)));

constexpr int S = 400, B = 32, T = 32, V = 50000, OOV = 50, E = 128, H = 256;
constexpr int VO = V + OOV, SB = S * B;
constexpr int VP = 50048;           // fp8 pbuf row stride
constexpr int NWG = 256;            // coop decoder workgroups (1 per CU)

DEV ushort f2bf(float x) {
    union { float f; unsigned u; } a; a.f = x;
    unsigned r = (a.u + 0x7fffu + ((a.u >> 16) & 1u)) >> 16;
    return (ushort)r;
}
DEV float bf2f(unsigned b) {
    union { unsigned u; float f; } a; a.u = b << 16; return a.f;
}
DEV float sigmoidf_(float x) { return 1.0f / (1.0f + __expf(-x)); }
DEV float tanhf_(float x) { float e = __expf(2.0f * x); return 1.0f - 2.0f / (e + 1.0f); }
DEV h2f asH2(unsigned u) { union { unsigned u; h2f h; } x; x.u = u; return x.h; }

#if __has_builtin(__builtin_amdgcn_fdot2)
DEV float dot2(h2f a, h2f b, float c) { return __builtin_amdgcn_fdot2(a, b, c, false); }
#else
DEV float dot2(h2f a, h2f b, float c) { return c + (float)a.x * (float)b.x + (float)a.y * (float)b.y; }
#endif

// fp8 e4m3 manual encode/decode (positive values only: exp of logits)
DEV unsigned f2e4(float v) {
    union { float f; unsigned u; } a; a.f = v;
    unsigned u = a.u + 0x0007FFFFu + ((a.u >> 20) & 1u);
    int e = (int)((u >> 23) & 255) - 127 + 7;
    unsigned m = (u >> 20) & 7u;
    if (e <= 0) return 0u;
    if (e > 15) { e = 15; m = 6; }
    return (unsigned)((e << 3) | m);
}
DEV float e42f(unsigned b) {
    int e = (int)((b >> 3) & 15), m = (int)(b & 7);
    if (e == 0) return (float)m * 1.953125e-3f;
    union { unsigned u; float f; } a;
    a.u = ((unsigned)(e + 120) << 23) | ((unsigned)m << 20);
    return a.f;
}

// ---------------- workspace layout ----------------
constexpr size_t SZ_EMB2D  = (size_t)SB * E * 2;
constexpr size_t SZ_WIHCAT = (size_t)2048 * 128 * 2;
constexpr size_t SZ_BIASX  = 2048 * 4;
constexpr size_t SZ_WFEAT  = (size_t)512 * 512 * 2;
constexpr size_t SZ_WO2    = (size_t)V * H * 2;
constexpr size_t SZ_WHH2   = (size_t)2 * 64 * 512 * 16;
constexpr size_t SZ_WCAT   = (size_t)1024 * 896 * 4;
constexpr size_t SZ_BC     = 1024 * 4;
constexpr size_t SZ_CPG    = 256;
constexpr size_t SZ_WRHT   = (size_t)512 * 256 * 4;
constexpr size_t SZ_WRCT   = (size_t)512 * 256 * 4;
constexpr size_t SZ_EMBDEC = (size_t)T * B * E * 4;
constexpr size_t SZ_WZ     = 1664 * 4 + 256;
constexpr size_t SZ_WAFT   = (size_t)512 * 512 * 4;    // [k][d]
constexpr size_t SZ_WO1T   = (size_t)1024 * 256 * 4;   // [k][d] f32
constexpr size_t SZ_XPROJ  = (size_t)SB * 2048 * 2;    // aliased by fp8 pbuf later
constexpr size_t SZ_ENCOUT = (size_t)SB * 512 * 2;     // b-major bf16
constexpr size_t SZ_ENCFEAT= (size_t)SB * 512 * 2;     // b-major f16
constexpr size_t SZ_HFIN   = (size_t)2 * B * H * 4;
constexpr size_t SZ_HPP    = (size_t)2 * B * H * 4;
constexpr size_t SZ_CTXPP  = (size_t)2 * B * 512 * 4;
constexpr size_t SZ_DAF    = (size_t)B * 512 * 4;
constexpr size_t SZ_EXPS   = (size_t)SB * 4;
constexpr size_t SZ_PGEN   = (size_t)T * B * 4;
constexpr size_t SZ_HIDALL = (size_t)T * B * 256 * 2;
constexpr size_t SZ_BAR    = 256;

constexpr size_t OFF_EMB2D  = 0;
constexpr size_t OFF_WIHCAT = OFF_EMB2D  + SZ_EMB2D;
constexpr size_t OFF_BIASX  = OFF_WIHCAT + SZ_WIHCAT;
constexpr size_t OFF_WFEAT  = OFF_BIASX  + SZ_BIASX;
constexpr size_t OFF_WO2    = OFF_WFEAT  + SZ_WFEAT;
constexpr size_t OFF_WHH2   = OFF_WO2    + SZ_WO2;
constexpr size_t OFF_WCAT   = OFF_WHH2   + SZ_WHH2;
constexpr size_t OFF_BC     = OFF_WCAT   + SZ_WCAT;
constexpr size_t OFF_CPG    = OFF_BC     + SZ_BC;
constexpr size_t OFF_WRHT   = OFF_CPG    + SZ_CPG;
constexpr size_t OFF_WRCT   = OFF_WRHT   + SZ_WRHT;
constexpr size_t OFF_EMBDEC = OFF_WRCT   + SZ_WRCT;
constexpr size_t OFF_WZ     = OFF_EMBDEC + SZ_EMBDEC;
constexpr size_t OFF_WAFT   = OFF_WZ     + SZ_WZ;
constexpr size_t OFF_WO1T   = OFF_WAFT   + SZ_WAFT;
constexpr size_t OFF_XPROJ  = OFF_WO1T   + SZ_WO1T;
constexpr size_t OFF_ENCOUT = OFF_XPROJ  + SZ_XPROJ;
constexpr size_t OFF_ENCFEAT= OFF_ENCOUT + SZ_ENCOUT;
constexpr size_t OFF_HFIN   = OFF_ENCFEAT+ SZ_ENCFEAT;
constexpr size_t OFF_CFIN   = OFF_HFIN   + SZ_HFIN;
constexpr size_t OFF_HPP    = OFF_CFIN   + SZ_HFIN;
constexpr size_t OFF_CPP    = OFF_HPP    + SZ_HPP;
constexpr size_t OFF_CTXPP  = OFF_CPP    + SZ_HPP;
constexpr size_t OFF_DAF    = OFF_CTXPP  + SZ_CTXPP;
constexpr size_t OFF_EXPS   = OFF_DAF    + SZ_DAF;
constexpr size_t OFF_PGEN   = OFF_EXPS   + SZ_EXPS;
constexpr size_t OFF_HIDALL = OFF_PGEN   + SZ_PGEN;
constexpr size_t OFF_BAR    = OFF_HIDALL + SZ_HIDALL;
constexpr size_t OFF_PBUF   = OFF_XPROJ;   // xproj dead after encoder

// ---------------- prep ----------------
constexpr long P1 = 2048L*128;     // wihcat bf16
constexpr long P2 = 2048;          // biasx
constexpr long P3 = 512L*512;      // wfeat bf16
constexpr long P4 = (long)V*H;     // wo2 bf16
constexpr long P5 = 2L*64*512*4;   // whh2 dwords
constexpr long P6 = 1024L*896;     // wcat f32
constexpr long P7 = 1;             // cpg
constexpr long P8 = 1024;          // bcv
constexpr long P9 = (long)SB*E;    // emb2d
constexpr long P10 = 512L*256;     // wrhT
constexpr long P11 = 512L*256;     // wrcT
constexpr long P12 = 32L*32*128;   // embdec
constexpr long P13 = 1664;         // wz
constexpr long P14 = 512L*512;     // wafT
constexpr long P15 = 1024L*256;    // wo1T
constexpr long PREP_TOTAL = P1+P2+P3+P4+P5+P6+P7+P8+P9+P10+P11+P12+P13+P14+P15;

__global__ __launch_bounds__(256)
void prep_kernel(const float* __restrict__ Wih_f, const float* __restrict__ Wih_b,
                 const float* __restrict__ bih_f, const float* __restrict__ bhh_f,
                 const float* __restrict__ bih_b, const float* __restrict__ bhh_b,
                 const float* __restrict__ W_feat, const float* __restrict__ W_o2,
                 const float* __restrict__ Whh_f, const float* __restrict__ Whh_b,
                 const float* __restrict__ dWih, const float* __restrict__ W_ctx,
                 const float* __restrict__ W_pg, const float* __restrict__ b_pg,
                 const float* __restrict__ b_ctx, const float* __restrict__ dbih,
                 const float* __restrict__ dbhh, const float* __restrict__ emb,
                 const int* __restrict__ inputs, const float* __restrict__ dWhh,
                 const float* __restrict__ W_rh, const float* __restrict__ W_rc,
                 const int* __restrict__ toks, const float* __restrict__ W_af,
                 const float* __restrict__ W_o1,
                 ushort* __restrict__ emb2d, ushort* __restrict__ wihcat,
                 float* __restrict__ biasx, ushort* __restrict__ wfeatbf,
                 ushort* __restrict__ wo2bf, unsigned* __restrict__ whh2,
                 float* __restrict__ wcat, float* __restrict__ cpgp,
                 float* __restrict__ bcv, float* __restrict__ wrhT,
                 float* __restrict__ wrcT, float* __restrict__ embdec,
                 float* __restrict__ wz, float* __restrict__ wafT,
                 float* __restrict__ wo1T)
{
    long id = (long)blockIdx.x * 256 + threadIdx.x;
    if (id < P1) { int r = id >> 7, e = id & 127;
        float v = (r < 1024) ? Wih_f[r*128+e] : Wih_b[(r-1024)*128+e];
        wihcat[id] = f2bf(v); return; }
    id -= P1;
    if (id < P2) { biasx[id] = (id < 1024) ? bih_f[id]+bhh_f[id] : bih_b[id-1024]+bhh_b[id-1024]; return; }
    id -= P2;
    if (id < P3) { wfeatbf[id] = f2bf(W_feat[id]); return; }
    id -= P3;
    if (id < P4) { wo2bf[id] = f2bf(W_o2[id]); return; }
    id -= P4;
    if (id < P5) {
        int q = id & 3; long r = id >> 2;
        int t = (int)(r & 511); r >>= 9; int c = (int)(r & 63); int dir = (int)(r >> 6);
        int gate = c >> 4, p = c & 15, kh = t & 1;
        int j = t >> 1;
        int k0 = kh * 128 + p * 8 + 2 * q;
        int row = gate * 256 + j;
        const float* W = dir ? Whh_b : Whh_f;
        h2f hv; hv.x = (_Float16)W[(size_t)row*256 + k0]; hv.y = (_Float16)W[(size_t)row*256 + k0 + 1];
        whh2[id] = __builtin_bit_cast(unsigned, hv); return; }
    id -= P5;
    if (id < P6) { int col = (int)(id / 896), k = (int)(id % 896);
        if (k < 640) {
            float acc = 0.f;
            for (int e = 0; e < 128; ++e) acc += dWih[col*128+e] * W_ctx[e*640+k];
            wcat[id] = acc;
        } else wcat[id] = dWhh[(size_t)col*256 + (k - 640)];
        return; }
    id -= P6;
    if (id < P7) { float acc = b_pg[0];
        for (int e = 0; e < 128; ++e) acc += W_pg[1024+e] * b_ctx[e];
        cpgp[0] = acc; return; }
    id -= P7;
    if (id < P8) { float acc = dbih[id] + dbhh[id];
        for (int e = 0; e < 128; ++e) acc += dWih[id*128+e] * b_ctx[e];
        bcv[id] = acc; return; }
    id -= P8;
    if (id < P9) { long sb = id >> 7; int e = id & 127;
        emb2d[id] = f2bf(emb[(size_t)inputs[sb]*128 + e]); return; }
    id -= P9;
    if (id < P10) { int j = id & 255; long k = id >> 8;
        wrhT[id] = W_rh[(size_t)j * 512 + k]; return; }
    id -= P10;
    if (id < P11) { int j = id & 255; long k = id >> 8;
        wrcT[id] = W_rc[(size_t)j * 512 + k]; return; }
    id -= P11;
    if (id < P12) { long tb = id >> 7; int e = id & 127;
        embdec[id] = emb[(size_t)toks[tb]*128 + e]; return; }
    id -= P12;
    if (id < P13) {
        int k = (int)id;
        if (k < 1024) wz[k] = W_pg[k];
        else { int u = k - 1024; float acc = 0.f;
            for (int e = 0; e < 128; ++e) acc += W_pg[1024+e] * W_ctx[e*640+u];
            wz[k] = acc; }
        return; }
    id -= P13;
    if (id < P14) { int d = id & 511; long k = id >> 9;
        wafT[id] = W_af[(size_t)d * 512 + k]; return; }
    id -= P14;
    if (id < P15) { int d = id & 255; long k = id >> 8;
        wo1T[id] = W_o1[(size_t)d * 1024 + k]; return; }
}

// ---------------- generic bf16 MFMA GEMM ----------------
// MODE: 0 f32, 1 f16, 2 f32 exp, 4 fp8 exp
template<int BM, int BN, int NT, int MODE, bool BIAS, bool SWZ>
__global__ __launch_bounds__(NT)
void gemm_nt(const ushort* __restrict__ A, int lda, const ushort* __restrict__ Bm, int ldb,
             void* __restrict__ Cp, int ldc, const float* __restrict__ bias,
             int M, int N, int K)
{
    constexpr int WN = BN / 32;
    __shared__ ushort sA[BM * 32];
    __shared__ ushort sB[BN * 32];
    int tid = threadIdx.x, lane = tid & 63, wid = tid >> 6;
    int wm = wid / WN, wn = wid % WN;
    int mb = blockIdx.y, nb = blockIdx.x;
    if (SWZ) {
        int n = gridDim.x, x = nb & 7, y = nb >> 3, q = n >> 3, r = n & 7;
        nb = (x < r ? x * (q + 1) : r * (q + 1) + (x - r) * q) + y;
    }
    int l15 = lane & 15, lg = lane >> 4;
    f32x4 acc[2][2] = {};
    for (int k0 = 0; k0 < K; k0 += 32) {
        for (int idx = tid; idx < BM * 4; idx += NT) {
            int r = idx >> 2, kc = (idx & 3) << 3;
            int row = mb * BM + r;
            uint4 v = make_uint4(0u, 0u, 0u, 0u);
            if (row < M) v = *(const uint4*)(A + (size_t)row * lda + k0 + kc);
            *(uint4*)(&sA[r * 32 + kc]) = v;
        }
        for (int idx = tid; idx < BN * 4; idx += NT) {
            int r = idx >> 2, kc = (idx & 3) << 3;
            int row = nb * BN + r;
            uint4 v = make_uint4(0u, 0u, 0u, 0u);
            if (row < N) v = *(const uint4*)(Bm + (size_t)row * ldb + k0 + kc);
            *(uint4*)(&sB[r * 32 + kc]) = v;
        }
        __syncthreads();
        s16x8 a0 = *(const s16x8*)(&sA[(wm * 32 + l15) * 32 + lg * 8]);
        s16x8 a1 = *(const s16x8*)(&sA[(wm * 32 + 16 + l15) * 32 + lg * 8]);
        s16x8 b0 = *(const s16x8*)(&sB[(wn * 32 + l15) * 32 + lg * 8]);
        s16x8 b1 = *(const s16x8*)(&sB[(wn * 32 + 16 + l15) * 32 + lg * 8]);
        acc[0][0] = __builtin_amdgcn_mfma_f32_16x16x32_bf16(a0, b0, acc[0][0], 0, 0, 0);
        acc[0][1] = __builtin_amdgcn_mfma_f32_16x16x32_bf16(a0, b1, acc[0][1], 0, 0, 0);
        acc[1][0] = __builtin_amdgcn_mfma_f32_16x16x32_bf16(a1, b0, acc[1][0], 0, 0, 0);
        acc[1][1] = __builtin_amdgcn_mfma_f32_16x16x32_bf16(a1, b1, acc[1][1], 0, 0, 0);
        __syncthreads();
    }
    int cb = nb * BN + wn * 32, rb = mb * BM + wm * 32;
    #pragma unroll
    for (int mf = 0; mf < 2; ++mf)
    #pragma unroll
    for (int nf = 0; nf < 2; ++nf) {
        int col = cb + nf * 16 + l15;
        float bv = 0.f;
        if (BIAS) { if (col < N) bv = bias[col]; }
        #pragma unroll
        for (int r = 0; r < 4; ++r) {
            int row = rb + mf * 16 + lg * 4 + r;
            if (row < M && col < N) {
                float v = acc[mf][nf][r] + bv;
                if (MODE == 0)      ((float*)Cp)[(size_t)row * ldc + col] = v;
                else if (MODE == 1) ((ushort*)Cp)[(size_t)row * ldc + col] = __builtin_bit_cast(ushort, (_Float16)v);
                else if (MODE == 2) ((float*)Cp)[(size_t)row * ldc + col] = __expf(v);
                else                ((unsigned char*)Cp)[(size_t)row * ldc + col] = (unsigned char)f2e4(__expf(v));
            }
        }
    }
}

// ---------------- encoder (bank-padded) ----------------
__global__ __launch_bounds__(512, 2)
void enc_kernel(const ushort* __restrict__ xproj, const uint4* __restrict__ whh2,
                ushort* __restrict__ encoutB, float* __restrict__ hfin, float* __restrict__ cfin)
{
    __shared__ uint4  wlds[18 * 512];
    __shared__ __attribute__((aligned(16))) ushort hh16[2][2][136];
    int b = blockIdx.x & 31, dir = blockIdx.x >> 5;
    int t = threadIdx.x, j = t >> 1, kh = t & 1;
    const uint4* gw = whh2 + (size_t)dir * 64 * 512 + t;
    uint4 wreg[46];
    #pragma unroll
    for (int c = 0; c < 46; ++c) wreg[c] = gw[(size_t)c * 512];
    #pragma unroll
    for (int c = 46; c < 64; ++c) wlds[(c - 46) * 512 + t] = gw[(size_t)c * 512];
    if (t < 256) { hh16[0][t >> 7][t & 127] = 0; }
    float cst = 0.f, hst = 0.f;
    __syncthreads();
    const int khoff = kh * 512;
    #pragma unroll 1
    for (int step = 0; step < S; ++step) {
        int s = dir ? (S - 1 - step) : step;
        int cur = step & 1, nxt = cur ^ 1;
        const ushort* xp = xproj + ((size_t)(s * B + b)) * 2048 + dir * 1024 + j + khoff;
        ushort xra = xp[0], xrb = xp[256];
        float a0 = 0.f, a1 = 0.f, a2 = 0.f, a3 = 0.f;
        #pragma unroll
        for (int p = 0; p < 16; ++p) {
            uint4 hp = *(const uint4*)(&hh16[cur][kh][p * 8]);
            uint4 wi = wreg[p];
            uint4 wf = wreg[16 + p];
            uint4 wg = (p < 14) ? wreg[32 + p] : wlds[(p - 14) * 512 + t];
            uint4 wo = wlds[(p + 2) * 512 + t];
            h2f p0 = asH2(hp.x), p1 = asH2(hp.y), p2 = asH2(hp.z), p3 = asH2(hp.w);
            a0 = dot2(p0, asH2(wi.x), a0); a0 = dot2(p1, asH2(wi.y), a0);
            a0 = dot2(p2, asH2(wi.z), a0); a0 = dot2(p3, asH2(wi.w), a0);
            a1 = dot2(p0, asH2(wf.x), a1); a1 = dot2(p1, asH2(wf.y), a1);
            a1 = dot2(p2, asH2(wf.z), a1); a1 = dot2(p3, asH2(wf.w), a1);
            a2 = dot2(p0, asH2(wg.x), a2); a2 = dot2(p1, asH2(wg.y), a2);
            a2 = dot2(p2, asH2(wg.z), a2); a2 = dot2(p3, asH2(wg.w), a2);
            a3 = dot2(p0, asH2(wo.x), a3); a3 = dot2(p1, asH2(wo.y), a3);
            a3 = dot2(p2, asH2(wo.z), a3); a3 = dot2(p3, asH2(wo.w), a3);
        }
        float xv0 = (float)__builtin_bit_cast(_Float16, xra);
        float xv1 = (float)__builtin_bit_cast(_Float16, xrb);
        a0 += kh ? 0.f : xv0;  a1 += kh ? 0.f : xv1;
        a2 += kh ? xv0 : 0.f;  a3 += kh ? xv1 : 0.f;
        a0 += __shfl_xor(a0, 1); a1 += __shfl_xor(a1, 1);
        a2 += __shfl_xor(a2, 1); a3 += __shfl_xor(a3, 1);
        cst = sigmoidf_(a1) * cst + sigmoidf_(a0) * tanhf_(a2);
        hst = sigmoidf_(a3) * tanhf_(cst);
        if (kh == 0) {
            encoutB[((size_t)(b * S + s)) * 512 + dir * 256 + j] = f2bf(hst);
            hh16[nxt][j >> 7][j & 127] = __builtin_bit_cast(ushort, (_Float16)hst);
        }
        __syncthreads();
    }
    if (kh == 0) {
        hfin[(dir * 32 + b) * 256 + j] = hst;
        cfin[(dir * 32 + b) * 256 + j] = cst;
    }
}

// ---------------- decoder init ----------------
__global__ __launch_bounds__(256)
void initdec_kernel(const float* __restrict__ hfin, const float* __restrict__ cfin,
                    const float* __restrict__ wrhT, const float* __restrict__ b_rh,
                    const float* __restrict__ wrcT, const float* __restrict__ b_rc,
                    float* __restrict__ hPP, float* __restrict__ cPP, float* __restrict__ ctxPP)
{
    int b = blockIdx.x, j = threadIdx.x;
    float ah = b_rh[j], ac = b_rc[j];
    for (int k = 0; k < 512; ++k) {
        float hv = (k < 256) ? hfin[b * 256 + k] : hfin[(32 + b) * 256 + k - 256];
        float cv = (k < 256) ? cfin[b * 256 + k] : cfin[(32 + b) * 256 + k - 256];
        ah += hv * wrhT[k * 256 + j];
        ac += cv * wrcT[k * 256 + j];
    }
    hPP[b * 256 + j] = fmaxf(ah, 0.f);
    cPP[b * 256 + j] = fmaxf(ac, 0.f);
    ctxPP[b * 512 + j] = 0.f;
    ctxPP[b * 512 + 256 + j] = 0.f;
}

// ---------------- hid + pgen helpers ----------------
DEV void hid_block(int idx, int tid, const float* hin, const float* cin, const float* ctxin,
                   const float* wo1T, const float* b_o1, ushort* hid_prev,
                   float xs[8][1024], float redh[4][8][64])
{
    int bg = idx >> 2, dg = idx & 3;
    for (int i = tid; i < 8192; i += 256) {
        int b8 = i >> 10, k = i & 1023;
        int b = bg * 8 + b8;
        float v;
        if (k < 256)      v = hin[b * 256 + k];
        else if (k < 512) v = cin[b * 256 + k - 256];
        else              v = ctxin[b * 512 + (k - 512)];
        xs[b8][k] = v;
    }
    __syncthreads();
    int dl = tid & 63, kq = tid >> 6;
    int d = dg * 64 + dl;
    float acc8[8] = {};
    for (int k = kq * 256; k < kq * 256 + 256; k += 4) {
        float w0 = wo1T[(size_t)k * 256 + d];
        float w1 = wo1T[(size_t)(k + 1) * 256 + d];
        float w2 = wo1T[(size_t)(k + 2) * 256 + d];
        float w3 = wo1T[(size_t)(k + 3) * 256 + d];
        #pragma unroll
        for (int b8 = 0; b8 < 8; ++b8) {
            float4 x = *(const float4*)(&xs[b8][k]);
            acc8[b8] += w0 * x.x + w1 * x.y + w2 * x.z + w3 * x.w;
        }
    }
    #pragma unroll
    for (int b8 = 0; b8 < 8; ++b8) redh[kq][b8][dl] = acc8[b8];
    __syncthreads();
    for (int i = tid; i < 512; i += 256) {
        int b8 = i >> 6, dl2 = i & 63;
        int d2 = dg * 64 + dl2;
        float v = redh[0][b8][dl2] + redh[1][b8][dl2] + redh[2][b8][dl2] + redh[3][b8][dl2] + b_o1[d2];
        hid_prev[(size_t)(bg * 8 + b8) * 256 + d2] = f2bf(v);
    }
}

DEV void pgen_block(int tid, const float* hin, const float* cin, const float* ctxin,
                    const float* ctxold, const float* embprev, const float* wz,
                    const float* cpgp, float* pgen_prev)
{
    int pb = tid >> 3, sg = tid & 7;
    float acc = 0.f;
    for (int u = 0; u < 208; ++u) {
        int k = sg * 208 + u;
        float zv;
        if (k < 512)        zv = ctxin[pb * 512 + k];
        else if (k < 768)   zv = hin[pb * 256 + (k - 512)];
        else if (k < 1024)  zv = cin[pb * 256 + (k - 768)];
        else if (k < 1536)  zv = ctxold[pb * 512 + (k - 1024)];
        else                zv = embprev[pb * 128 + (k - 1536)];
        acc += wz[k] * zv;
    }
    acc += __shfl_xor(acc, 1); acc += __shfl_xor(acc, 2); acc += __shfl_xor(acc, 4);
    if (sg == 0) pgen_prev[pb] = sigmoidf_(acc + cpgp[0]);
}

// ---------------- persistent decoder v2: 256 WGs x 256 thr, 4 barriers/step ----------------
DEV void gridbar(unsigned* cnt, unsigned* gen) {
    __syncthreads();
    __threadfence();
    if (threadIdx.x == 0) {
        unsigned g = __hip_atomic_load(gen, __ATOMIC_RELAXED, __HIP_MEMORY_SCOPE_AGENT);
        unsigned a = __hip_atomic_fetch_add(cnt, 1u, __ATOMIC_ACQ_REL, __HIP_MEMORY_SCOPE_AGENT);
        if (a == (unsigned)(NWG - 1)) {
            __hip_atomic_store(cnt, 0u, __ATOMIC_RELAXED, __HIP_MEMORY_SCOPE_AGENT);
            __hip_atomic_store(gen, g + 1u, __ATOMIC_RELEASE, __HIP_MEMORY_SCOPE_AGENT);
        } else {
            while (__hip_atomic_load(gen, __ATOMIC_ACQUIRE, __HIP_MEMORY_SCOPE_AGENT) == g)
                __builtin_amdgcn_s_sleep(2);
        }
        __threadfence();
    }
    __syncthreads();
}

__global__ __launch_bounds__(256)
void coopdec2_kernel(const float* __restrict__ wcat, const float* __restrict__ bcv,
                     const float* __restrict__ embdec,
                     const float* __restrict__ wafT, const float* __restrict__ b_af,
                     const ushort* __restrict__ encfeatB, const float* __restrict__ wv,
                     const int* __restrict__ inputs, const ushort* __restrict__ encoutB,
                     const float* __restrict__ wo1T, const float* __restrict__ b_o1,
                     const float* __restrict__ wz, const float* __restrict__ cpgp,
                     float* __restrict__ hPP, float* __restrict__ cPP,
                     float* __restrict__ ctxPP, float* __restrict__ daf,
                     float* __restrict__ exps,
                     float* __restrict__ pgenAll, ushort* __restrict__ hidAll,
                     float* __restrict__ atts,
                     unsigned* __restrict__ barcnt, unsigned* __restrict__ bargen)
{
    __shared__ float pre[256];
    __shared__ float xs[8][1024];
    __shared__ float redh[4][8][64];
    __shared__ float xs4[4][512];
    __shared__ float redB[4][4][64];
    __shared__ float wvL[512];
    __shared__ float sc[400];
    __shared__ float redn[256];
    __shared__ float red2[4][128];

    int wg = blockIdx.x, tid = threadIdx.x;
    wvL[tid] = wv[tid]; wvL[tid + 256] = wv[tid + 256];
    __syncthreads();

    for (int t = 0; t < T; ++t) {
        int p = t & 1, q = p ^ 1;
        const float* ctxin  = ctxPP + (size_t)p * 16384;
        const float* ctxold = ctxPP + (size_t)q * 16384;   // ctx_{t-2}
        const float* hin = hPP + (size_t)p * 8192;
        const float* cin = cPP + (size_t)p * 8192;
        float* hout = hPP + (size_t)q * 8192;
        float* cout = cPP + (size_t)q * 8192;
        const float* embt = embdec + (size_t)t * 4096;

        // ---- phase A: lstm (wg<128) | hid(t-1) (128..143) | pgen(t-1) (144) ----
        if (wg < 128) {
            int b = tid & 31, ci = tid >> 5;
            int gi = ci >> 1, jj = ci & 1;
            int j = (wg << 1) + jj;
            int col = gi * 256 + j;
            float acc = bcv[col];
            const float4* w = (const float4*)(wcat + (size_t)col * 896);
            const float4* x0 = (const float4*)(ctxin + b * 512);
            #pragma unroll 8
            for (int u = 0; u < 128; ++u) { float4 a = w[u], qv = x0[u]; acc += a.x*qv.x + a.y*qv.y + a.z*qv.z + a.w*qv.w; }
            const float4* x1 = (const float4*)(embt + b * 128);
            #pragma unroll 8
            for (int u = 0; u < 32; ++u) { float4 a = w[128 + u], qv = x1[u]; acc += a.x*qv.x + a.y*qv.y + a.z*qv.z + a.w*qv.w; }
            const float4* x2 = (const float4*)(hin + b * 256);
            #pragma unroll 8
            for (int u = 0; u < 64; ++u) { float4 a = w[160 + u], qv = x2[u]; acc += a.x*qv.x + a.y*qv.y + a.z*qv.z + a.w*qv.w; }
            pre[tid] = acc;
            __syncthreads();
            if (tid < 64) {
                int b2 = tid & 31, qq = tid >> 5;
                int j2 = (wg << 1) + qq;
                float iv = pre[(0 + qq) * 32 + b2];
                float fv = pre[(2 + qq) * 32 + b2];
                float gv = pre[(4 + qq) * 32 + b2];
                float ov = pre[(6 + qq) * 32 + b2];
                float cp = cin[b2 * 256 + j2];
                float cn = sigmoidf_(fv) * cp + sigmoidf_(iv) * tanhf_(gv);
                float hn = sigmoidf_(ov) * tanhf_(cn);
                cout[b2 * 256 + j2] = cn;
                hout[b2 * 256 + j2] = hn;
            }
        } else if (wg < 144) {
            if (t > 0)
                hid_block(wg - 128, tid, hin, cin, ctxin, wo1T, b_o1,
                          hidAll + (size_t)(t - 1) * 8192, xs, redh);
        } else if (wg == 144) {
            if (t > 0)
                pgen_block(tid, hin, cin, ctxin, ctxold,
                           embdec + (size_t)(t - 1) * 4096, wz, cpgp,
                           pgenAll + (size_t)(t - 1) * 32);
        }
        gridbar(barcnt, bargen);

        // ---- phase B: daf (wg<64): bg = wg>>3 (4 b), dg = wg&7 (64 d) ----
        if (wg < 64) {
            int bg = wg >> 3, dg = wg & 7;
            for (int i = tid; i < 2048; i += 256) {
                int b4 = i >> 9, k = i & 511;
                int b = bg * 4 + b4;
                xs4[b4][k] = (k < 256) ? hout[b * 256 + k] : cout[b * 256 + k - 256];
            }
            __syncthreads();
            int dl = tid & 63, kq = tid >> 6;
            int d = dg * 64 + dl;
            float acc4[4] = {};
            for (int k = kq * 128; k < kq * 128 + 128; k += 4) {
                float w0 = wafT[(size_t)k * 512 + d];
                float w1 = wafT[(size_t)(k + 1) * 512 + d];
                float w2 = wafT[(size_t)(k + 2) * 512 + d];
                float w3 = wafT[(size_t)(k + 3) * 512 + d];
                #pragma unroll
                for (int b4 = 0; b4 < 4; ++b4) {
                    float4 x = *(const float4*)(&xs4[b4][k]);
                    acc4[b4] += w0 * x.x + w1 * x.y + w2 * x.z + w3 * x.w;
                }
            }
            #pragma unroll
            for (int b4 = 0; b4 < 4; ++b4) redB[kq][b4][dl] = acc4[b4];
            __syncthreads();
            {
                int b4 = tid >> 6, dl2 = tid & 63;
                int d2 = dg * 64 + dl2;
                daf[(size_t)(bg * 4 + b4) * 512 + d2] =
                    redB[0][b4][dl2] + redB[1][b4][dl2] + redB[2][b4][dl2] + redB[3][b4][dl2] + b_af[d2];
            }
        }
        gridbar(barcnt, bargen);

        // ---- phase C: e -> exp; wg handles s = wg and s = wg + 256 ----
        for (int rep = 0; rep < 2; ++rep) {
            int s = wg + rep * 256;
            if (s >= 400) break;
            int w = tid >> 6, l = tid & 63;
            #pragma unroll 1
            for (int i = 0; i < 8; ++i) {
                int b = w * 8 + i;
                uint4 u = *(const uint4*)(encfeatB + ((size_t)b * S + s) * 512 + l * 8);
                const float4* dr = (const float4*)(daf + (size_t)b * 512 + l * 8);
                float4 d0 = dr[0], d1 = dr[1];
                float4 w0 = *(const float4*)(wvL + l * 8);
                float4 w1 = *(const float4*)(wvL + l * 8 + 4);
                h2f e0 = asH2(u.x), e1 = asH2(u.y), e2 = asH2(u.z), e3 = asH2(u.w);
                float e = tanhf_((float)e0.x + d0.x) * w0.x + tanhf_((float)e0.y + d0.y) * w0.y
                        + tanhf_((float)e1.x + d0.z) * w0.z + tanhf_((float)e1.y + d0.w) * w0.w
                        + tanhf_((float)e2.x + d1.x) * w1.x + tanhf_((float)e2.y + d1.y) * w1.y
                        + tanhf_((float)e3.x + d1.z) * w1.z + tanhf_((float)e3.y + d1.w) * w1.w;
                e += __shfl_xor(e, 1);  e += __shfl_xor(e, 2);
                e += __shfl_xor(e, 4);  e += __shfl_xor(e, 8);
                e += __shfl_xor(e, 16); e += __shfl_xor(e, 32);
                if (l == 0) {
                    float m = (inputs[s * 32 + b] != 0) ? 1.f : 0.f;
                    exps[s * 32 + b] = m * __expf(e);
                }
            }
        }
        gridbar(barcnt, bargen);

        // ---- phase D: normalize + atts + ctx (wg<128): b = wg>>2, dg = wg&3 ----
        if (wg < 128) {
            int b = wg >> 2, dg = wg & 3;
            float part = 0.f;
            for (int s = tid; s < 400; s += 256) { float v = exps[s * 32 + b]; sc[s] = v; part += v; }
            redn[tid] = part;
            __syncthreads();
            for (int o = 128; o > 0; o >>= 1) { if (tid < o) redn[tid] += redn[tid + o]; __syncthreads(); }
            float rinv = 1.f / redn[0];
            if (dg == 0) for (int s = tid; s < 400; s += 256) atts[(size_t)t * SB + s * 32 + b] = sc[s] * rinv;
            int sp = tid >> 6, dl = tid & 63;
            float a0 = 0.f, a1 = 0.f;
            const ushort* ebase = encoutB + (size_t)b * S * 512 + dg * 128 + dl * 2;
            #pragma unroll 4
            for (int s = sp; s < 400; s += 4) {
                float a = sc[s];
                unsigned u = *(const unsigned*)(ebase + (size_t)s * 512);
                a0 += a * bf2f(u & 0xffffu);
                a1 += a * bf2f(u >> 16);
            }
            red2[sp][dl * 2] = a0;
            red2[sp][dl * 2 + 1] = a1;
            __syncthreads();
            if (tid < 128) {
                float v = (red2[0][tid] + red2[1][tid] + red2[2][tid] + red2[3][tid]) * rinv;
                ctxPP[(size_t)q * 16384 + (size_t)b * 512 + dg * 128 + tid] = v;
            }
        }
        gridbar(barcnt, bargen);
    }

    // ---- tail: hid + pgen for t = T-1 (state slot p = T&1 = 0) ----
    if (wg >= 128 && wg < 144) {
        hid_block(wg - 128, tid, hPP, cPP, ctxPP, wo1T, b_o1,
                  hidAll + (size_t)(T - 1) * 8192, xs, redh);
    } else if (wg == 144) {
        pgen_block(tid, hPP, cPP, ctxPP, ctxPP + 16384,
                   embdec + (size_t)(T - 1) * 4096, wz, cpgp,
                   pgenAll + (size_t)(T - 1) * 32);
    }
}

// ---------------- batched out: fp8 row-sum, scale+write, scatter ----------------
__global__ __launch_bounds__(256)
void dec_out2_kernel(const unsigned char* __restrict__ pbuf, const float* __restrict__ pgenAll,
                     const int* __restrict__ tex, const float* __restrict__ attsAll,
                     float* __restrict__ outsAll)
{
    int tb = blockIdx.x, t = threadIdx.x;
    int tstep = tb >> 5, b = tb & 31;
    const unsigned char* prow = pbuf + (size_t)tb * VP;
    float part = 0.f;
    for (int i = t; i < V / 8; i += 256) {
        uint2 u = *(const uint2*)(prow + i * 8);
        unsigned w0 = u.x, w1 = u.y;
        part += e42f(w0 & 255) + e42f((w0 >> 8) & 255) + e42f((w0 >> 16) & 255) + e42f(w0 >> 24);
        part += e42f(w1 & 255) + e42f((w1 >> 8) & 255) + e42f((w1 >> 16) & 255) + e42f(w1 >> 24);
    }
    __shared__ float red[256];
    red[t] = part;
    __syncthreads();
    for (int o = 128; o > 0; o >>= 1) { if (t < o) red[t] += red[t + o]; __syncthreads(); }
    float pg = pgenAll[tb];
    float sca = pg / red[0];
    float om = 1.f - pg;
    float* orow = outsAll + (size_t)tstep * B * VO + (size_t)b * VO;
    for (int i = t; i < V / 8; i += 256) {
        uint2 u = *(const uint2*)(prow + i * 8);
        unsigned w0 = u.x, w1 = u.y;
        float2* o2 = (float2*)(orow + i * 8);
        o2[0] = make_float2(e42f(w0 & 255) * sca, e42f((w0 >> 8) & 255) * sca);
        o2[1] = make_float2(e42f((w0 >> 16) & 255) * sca, e42f(w0 >> 24) * sca);
        o2[2] = make_float2(e42f(w1 & 255) * sca, e42f((w1 >> 8) & 255) * sca);
        o2[3] = make_float2(e42f((w1 >> 16) & 255) * sca, e42f(w1 >> 24) * sca);
    }
    if (t < OOV) orow[V + t] = 0.f;
    __syncthreads();
    const float* attst = attsAll + (size_t)tstep * SB;
    for (int si = t; si < 400; si += 256)
        atomicAdd(orow + tex[si * 32 + b], om * attst[si * 32 + b]);
}

// ---------------- host ----------------
extern "C" void kernel_launch(void* const* d_in, const int* in_sizes, int n_in,
                              void* d_out, int out_size, void* d_ws, size_t ws_size,
                              hipStream_t stream)
{
    const int*   inputs  = (const int*)d_in[0];
    const int*   toksAll = (const int*)d_in[2];
    const int*   tex     = (const int*)d_in[3];
    const float* emb     = (const float*)d_in[5];
    const float* Wih_f   = (const float*)d_in[6];
    const float* Whh_f   = (const float*)d_in[7];
    const float* bih_f   = (const float*)d_in[8];
    const float* bhh_f   = (const float*)d_in[9];
    const float* Wih_b   = (const float*)d_in[10];
    const float* Whh_b   = (const float*)d_in[11];
    const float* bih_b   = (const float*)d_in[12];
    const float* bhh_b   = (const float*)d_in[13];
    const float* W_feat  = (const float*)d_in[14];
    const float* W_rh    = (const float*)d_in[15];
    const float* b_rh    = (const float*)d_in[16];
    const float* W_rc    = (const float*)d_in[17];
    const float* b_rc    = (const float*)d_in[18];
    const float* W_af    = (const float*)d_in[19];
    const float* b_af    = (const float*)d_in[20];
    const float* w_v     = (const float*)d_in[21];
    const float* W_ctx   = (const float*)d_in[22];
    const float* b_ctx   = (const float*)d_in[23];
    const float* dWih    = (const float*)d_in[24];
    const float* dWhh    = (const float*)d_in[25];
    const float* dbih    = (const float*)d_in[26];
    const float* dbhh    = (const float*)d_in[27];
    const float* W_pg    = (const float*)d_in[28];
    const float* b_pg    = (const float*)d_in[29];
    const float* W_o1    = (const float*)d_in[30];
    const float* b_o1    = (const float*)d_in[31];
    const float* W_o2    = (const float*)d_in[32];
    const float* b_o2    = (const float*)d_in[33];

    char* wsb = (char*)d_ws;
    ushort*   emb2d   = (ushort*)(wsb + OFF_EMB2D);
    ushort*   wihcat  = (ushort*)(wsb + OFF_WIHCAT);
    float*    biasx   = (float*)(wsb + OFF_BIASX);
    ushort*   wfeatbf = (ushort*)(wsb + OFF_WFEAT);
    ushort*   wo2bf   = (ushort*)(wsb + OFF_WO2);
    unsigned* whh2    = (unsigned*)(wsb + OFF_WHH2);
    float*    wcat    = (float*)(wsb + OFF_WCAT);
    float*    bcv     = (float*)(wsb + OFF_BC);
    float*    cpgp    = (float*)(wsb + OFF_CPG);
    float*    wrhT    = (float*)(wsb + OFF_WRHT);
    float*    wrcT    = (float*)(wsb + OFF_WRCT);
    float*    embdec  = (float*)(wsb + OFF_EMBDEC);
    float*    wz      = (float*)(wsb + OFF_WZ);
    float*    wafT    = (float*)(wsb + OFF_WAFT);
    float*    wo1T    = (float*)(wsb + OFF_WO1T);
    ushort*   xproj   = (ushort*)(wsb + OFF_XPROJ);
    ushort*   encoutB = (ushort*)(wsb + OFF_ENCOUT);
    ushort*   encfeatB= (ushort*)(wsb + OFF_ENCFEAT);
    float*    hfin    = (float*)(wsb + OFF_HFIN);
    float*    cfin    = (float*)(wsb + OFF_CFIN);
    float*    hPP     = (float*)(wsb + OFF_HPP);
    float*    cPP     = (float*)(wsb + OFF_CPP);
    float*    ctxPP   = (float*)(wsb + OFF_CTXPP);
    float*    daf     = (float*)(wsb + OFF_DAF);
    float*    exps    = (float*)(wsb + OFF_EXPS);
    float*    pgenAll = (float*)(wsb + OFF_PGEN);
    ushort*   hidAll  = (ushort*)(wsb + OFF_HIDALL);
    unsigned* barbuf  = (unsigned*)(wsb + OFF_BAR);
    unsigned char* pbuf = (unsigned char*)(wsb + OFF_PBUF);

    float* outs = (float*)d_out;
    float* atts = outs + (size_t)T * B * VO;

    int prep_blocks = (int)((PREP_TOTAL + 255) / 256);
    prep_kernel<<<prep_blocks, 256, 0, stream>>>(
        Wih_f, Wih_b, bih_f, bhh_f, bih_b, bhh_b, W_feat, W_o2, Whh_f, Whh_b,
        dWih, W_ctx, W_pg, b_pg, b_ctx, dbih, dbhh, emb, inputs, dWhh, W_rh, W_rc,
        toksAll, W_af, W_o1,
        emb2d, wihcat, biasx, wfeatbf, wo2bf, whh2, wcat, cpgp, bcv, wrhT, wrcT,
        embdec, wz, wafT, wo1T);

    gemm_nt<64, 64, 256, 1, true, false><<<dim3(2048 / 64, SB / 64), 256, 0, stream>>>(
        emb2d, 128, wihcat, 128, (void*)xproj, 2048, biasx, SB, 2048, 128);

    enc_kernel<<<64, 512, 0, stream>>>(xproj, (const uint4*)whh2, encoutB, hfin, cfin);

    initdec_kernel<<<32, 256, 0, stream>>>(hfin, cfin, wrhT, b_rh, wrcT, b_rc, hPP, cPP, ctxPP);

    gemm_nt<64, 64, 256, 1, false, false><<<dim3(512 / 64, SB / 64), 256, 0, stream>>>(
        encoutB, 512, wfeatbf, 512, (void*)encfeatB, 512, nullptr, SB, 512, 512);

    hipMemsetAsync(barbuf, 0, 16, stream);
    coopdec2_kernel<<<NWG, 256, 0, stream>>>(
        wcat, bcv, embdec, wafT, b_af, encfeatB, w_v, inputs, encoutB,
        wo1T, b_o1, wz, cpgp, hPP, cPP, ctxPP, daf, exps,
        pgenAll, hidAll, atts, barbuf, barbuf + 1);

    gemm_nt<64, 128, 512, 4, true, true><<<dim3(391, 16), 512, 0, stream>>>(
        hidAll, 256, wo2bf, 256, (void*)pbuf, VP, b_o2, T * B, V, 256);
    dec_out2_kernel<<<T * B, 256, 0, stream>>>(pbuf, pgenAll, tex, atts, outs);
}

// Round 7
// 4515.371 us; speedup vs baseline: 4.0588x; 4.0588x over previous
//
#include <hip/hip_runtime.h>

#define DEV static __device__ __forceinline__

typedef short  s16x8 __attribute__((ext_vector_type(8)));
typedef float  f32x4 __attribute__((ext_vector_type(4)));
typedef _Float16 h2f __attribute__((ext_vector_type(2)));

constexpr int S = 400, B = 32, T = 32, V = 50000, OOV = 50, E = 128, H = 256;
constexpr int VO = V + OOV, SB = S * B;
constexpr int VP = 50048;           // fp8 pbuf row stride

DEV ushort f2bf(float x) {
    union { float f; unsigned u; } a; a.f = x;
    unsigned r = (a.u + 0x7fffu + ((a.u >> 16) & 1u)) >> 16;
    return (ushort)r;
}
DEV float bf2f(unsigned b) {
    union { unsigned u; float f; } a; a.u = b << 16; return a.f;
}
DEV float sigmoidf_(float x) { return 1.0f / (1.0f + __expf(-x)); }
DEV float tanhf_(float x) { float e = __expf(2.0f * x); return 1.0f - 2.0f / (e + 1.0f); }
DEV h2f asH2(unsigned u) { union { unsigned u; h2f h; } x; x.u = u; return x.h; }

#if __has_builtin(__builtin_amdgcn_fdot2)
DEV float dot2(h2f a, h2f b, float c) { return __builtin_amdgcn_fdot2(a, b, c, false); }
#else
DEV float dot2(h2f a, h2f b, float c) { return c + (float)a.x * (float)b.x + (float)a.y * (float)b.y; }
#endif

// fp8 e4m3 manual encode/decode (positive values only: exp of logits)
DEV unsigned f2e4(float v) {
    union { float f; unsigned u; } a; a.f = v;
    unsigned u = a.u + 0x0007FFFFu + ((a.u >> 20) & 1u);
    int e = (int)((u >> 23) & 255) - 127 + 7;
    unsigned m = (u >> 20) & 7u;
    if (e <= 0) return 0u;
    if (e > 15) { e = 15; m = 6; }
    return (unsigned)((e << 3) | m);
}
DEV float e42f(unsigned b) {
    int e = (int)((b >> 3) & 15), m = (int)(b & 7);
    if (e == 0) return (float)m * 1.953125e-3f;
    union { unsigned u; float f; } a;
    a.u = ((unsigned)(e + 120) << 23) | ((unsigned)m << 20);
    return a.f;
}

// ---------------- workspace layout ----------------
constexpr size_t SZ_EMB2D  = (size_t)SB * E * 2;
constexpr size_t SZ_WIHCAT = (size_t)2048 * 128 * 2;
constexpr size_t SZ_BIASX  = 2048 * 4;
constexpr size_t SZ_WFEAT  = (size_t)512 * 512 * 2;
constexpr size_t SZ_WO2    = (size_t)V * H * 2;
constexpr size_t SZ_WHH2   = (size_t)2 * 64 * 512 * 16;
constexpr size_t SZ_WCAT   = (size_t)1024 * 896 * 4;
constexpr size_t SZ_BC     = 1024 * 4;
constexpr size_t SZ_CPG    = 256;
constexpr size_t SZ_WRHT   = (size_t)512 * 256 * 4;
constexpr size_t SZ_WRCT   = (size_t)512 * 256 * 4;
constexpr size_t SZ_EMBDEC = (size_t)T * B * E * 4;
constexpr size_t SZ_WZ     = 1664 * 4 + 256;
constexpr size_t SZ_WAFT   = (size_t)512 * 512 * 4;    // holds bf16 wafbf (first 512KB)
constexpr size_t SZ_WO1T   = (size_t)1024 * 256 * 4;   // [k][d] f32
constexpr size_t SZ_XPROJ  = (size_t)SB * 2048 * 2;    // aliased by fp8 pbuf later
constexpr size_t SZ_ENCOUT = (size_t)SB * 512 * 2;     // b-major bf16
constexpr size_t SZ_ENCFEAT= (size_t)SB * 512 * 2;     // b-major f16
constexpr size_t SZ_HFIN   = (size_t)2 * B * H * 4;
constexpr size_t SZ_HPP    = (size_t)2 * B * H * 4;
constexpr size_t SZ_CTXPP  = (size_t)2 * B * 512 * 4;
constexpr size_t SZ_DAF    = (size_t)B * 512 * 4;
constexpr size_t SZ_EXPS   = (size_t)SB * 4;
constexpr size_t SZ_PGEN   = (size_t)T * B * 4;
constexpr size_t SZ_HIDALL = (size_t)T * B * 256 * 2;

constexpr size_t OFF_EMB2D  = 0;
constexpr size_t OFF_WIHCAT = OFF_EMB2D  + SZ_EMB2D;
constexpr size_t OFF_BIASX  = OFF_WIHCAT + SZ_WIHCAT;
constexpr size_t OFF_WFEAT  = OFF_BIASX  + SZ_BIASX;
constexpr size_t OFF_WO2    = OFF_WFEAT  + SZ_WFEAT;
constexpr size_t OFF_WHH2   = OFF_WO2    + SZ_WO2;
constexpr size_t OFF_WCAT   = OFF_WHH2   + SZ_WHH2;
constexpr size_t OFF_BC     = OFF_WCAT   + SZ_WCAT;
constexpr size_t OFF_CPG    = OFF_BC     + SZ_BC;
constexpr size_t OFF_WRHT   = OFF_CPG    + SZ_CPG;
constexpr size_t OFF_WRCT   = OFF_WRHT   + SZ_WRHT;
constexpr size_t OFF_EMBDEC = OFF_WRCT   + SZ_WRCT;
constexpr size_t OFF_WZ     = OFF_EMBDEC + SZ_EMBDEC;
constexpr size_t OFF_WAFT   = OFF_WZ     + SZ_WZ;
constexpr size_t OFF_WO1T   = OFF_WAFT   + SZ_WAFT;
constexpr size_t OFF_XPROJ  = OFF_WO1T   + SZ_WO1T;
constexpr size_t OFF_ENCOUT = OFF_XPROJ  + SZ_XPROJ;
constexpr size_t OFF_ENCFEAT= OFF_ENCOUT + SZ_ENCOUT;
constexpr size_t OFF_HFIN   = OFF_ENCFEAT+ SZ_ENCFEAT;
constexpr size_t OFF_CFIN   = OFF_HFIN   + SZ_HFIN;
constexpr size_t OFF_HPP    = OFF_CFIN   + SZ_HFIN;
constexpr size_t OFF_CPP    = OFF_HPP    + SZ_HPP;
constexpr size_t OFF_CTXPP  = OFF_CPP    + SZ_HPP;
constexpr size_t OFF_DAF    = OFF_CTXPP  + SZ_CTXPP;
constexpr size_t OFF_EXPS   = OFF_DAF    + SZ_DAF;
constexpr size_t OFF_PGEN   = OFF_EXPS   + SZ_EXPS;
constexpr size_t OFF_HIDALL = OFF_PGEN   + SZ_PGEN;
constexpr size_t OFF_PBUF   = OFF_XPROJ;   // xproj dead after encoder

// ---------------- prep ----------------
constexpr long P1 = 2048L*128;     // wihcat bf16
constexpr long P2 = 2048;          // biasx
constexpr long P3 = 512L*512;      // wfeat bf16
constexpr long P4 = (long)V*H;     // wo2 bf16
constexpr long P5 = 2L*64*512*4;   // whh2 dwords
constexpr long P6 = 1024L*896;     // wcat f32
constexpr long P7 = 1;             // cpg
constexpr long P8 = 1024;          // bcv
constexpr long P9 = (long)SB*E;    // emb2d
constexpr long P10 = 512L*256;     // wrhT
constexpr long P11 = 512L*256;     // wrcT
constexpr long P12 = 32L*32*128;   // embdec
constexpr long P13 = 1664;         // wz
constexpr long P14 = 512L*512;     // wafbf (bf16, [k][d])
constexpr long P15 = 1024L*256;    // wo1T
constexpr long PREP_TOTAL = P1+P2+P3+P4+P5+P6+P7+P8+P9+P10+P11+P12+P13+P14+P15;

__global__ __launch_bounds__(256)
void prep_kernel(const float* __restrict__ Wih_f, const float* __restrict__ Wih_b,
                 const float* __restrict__ bih_f, const float* __restrict__ bhh_f,
                 const float* __restrict__ bih_b, const float* __restrict__ bhh_b,
                 const float* __restrict__ W_feat, const float* __restrict__ W_o2,
                 const float* __restrict__ Whh_f, const float* __restrict__ Whh_b,
                 const float* __restrict__ dWih, const float* __restrict__ W_ctx,
                 const float* __restrict__ W_pg, const float* __restrict__ b_pg,
                 const float* __restrict__ b_ctx, const float* __restrict__ dbih,
                 const float* __restrict__ dbhh, const float* __restrict__ emb,
                 const int* __restrict__ inputs, const float* __restrict__ dWhh,
                 const float* __restrict__ W_rh, const float* __restrict__ W_rc,
                 const int* __restrict__ toks, const float* __restrict__ W_af,
                 const float* __restrict__ W_o1,
                 ushort* __restrict__ emb2d, ushort* __restrict__ wihcat,
                 float* __restrict__ biasx, ushort* __restrict__ wfeatbf,
                 ushort* __restrict__ wo2bf, unsigned* __restrict__ whh2,
                 float* __restrict__ wcat, float* __restrict__ cpgp,
                 float* __restrict__ bcv, float* __restrict__ wrhT,
                 float* __restrict__ wrcT, float* __restrict__ embdec,
                 float* __restrict__ wz, ushort* __restrict__ wafbf,
                 float* __restrict__ wo1T)
{
    long id = (long)blockIdx.x * 256 + threadIdx.x;
    if (id < P1) { int r = id >> 7, e = id & 127;
        float v = (r < 1024) ? Wih_f[r*128+e] : Wih_b[(r-1024)*128+e];
        wihcat[id] = f2bf(v); return; }
    id -= P1;
    if (id < P2) { biasx[id] = (id < 1024) ? bih_f[id]+bhh_f[id] : bih_b[id-1024]+bhh_b[id-1024]; return; }
    id -= P2;
    if (id < P3) { wfeatbf[id] = f2bf(W_feat[id]); return; }
    id -= P3;
    if (id < P4) { wo2bf[id] = f2bf(W_o2[id]); return; }
    id -= P4;
    if (id < P5) {
        int q = id & 3; long r = id >> 2;
        int t = (int)(r & 511); r >>= 9; int c = (int)(r & 63); int dir = (int)(r >> 6);
        int gate = c >> 4, p = c & 15, kh = t & 1;
        int j = t >> 1;
        int k0 = kh * 128 + p * 8 + 2 * q;
        int row = gate * 256 + j;
        const float* W = dir ? Whh_b : Whh_f;
        h2f hv; hv.x = (_Float16)W[(size_t)row*256 + k0]; hv.y = (_Float16)W[(size_t)row*256 + k0 + 1];
        whh2[id] = __builtin_bit_cast(unsigned, hv); return; }
    id -= P5;
    if (id < P6) { int col = (int)(id / 896), k = (int)(id % 896);
        if (k < 640) {
            float acc = 0.f;
            for (int e = 0; e < 128; ++e) acc += dWih[col*128+e] * W_ctx[e*640+k];
            wcat[id] = acc;
        } else wcat[id] = dWhh[(size_t)col*256 + (k - 640)];
        return; }
    id -= P6;
    if (id < P7) { float acc = b_pg[0];
        for (int e = 0; e < 128; ++e) acc += W_pg[1024+e] * b_ctx[e];
        cpgp[0] = acc; return; }
    id -= P7;
    if (id < P8) { float acc = dbih[id] + dbhh[id];
        for (int e = 0; e < 128; ++e) acc += dWih[id*128+e] * b_ctx[e];
        bcv[id] = acc; return; }
    id -= P8;
    if (id < P9) { long sb = id >> 7; int e = id & 127;
        emb2d[id] = f2bf(emb[(size_t)inputs[sb]*128 + e]); return; }
    id -= P9;
    if (id < P10) { int j = id & 255; long k = id >> 8;
        wrhT[id] = W_rh[(size_t)j * 512 + k]; return; }
    id -= P10;
    if (id < P11) { int j = id & 255; long k = id >> 8;
        wrcT[id] = W_rc[(size_t)j * 512 + k]; return; }
    id -= P11;
    if (id < P12) { long tb = id >> 7; int e = id & 127;
        embdec[id] = emb[(size_t)toks[tb]*128 + e]; return; }
    id -= P12;
    if (id < P13) {
        int k = (int)id;
        if (k < 1024) wz[k] = W_pg[k];
        else { int u = k - 1024; float acc = 0.f;
            for (int e = 0; e < 128; ++e) acc += W_pg[1024+e] * W_ctx[e*640+u];
            wz[k] = acc; }
        return; }
    id -= P13;
    if (id < P14) { int d = id & 511; long k = id >> 9;   // wafbf[k][d]
        wafbf[id] = f2bf(W_af[(size_t)d * 512 + k]); return; }
    id -= P14;
    if (id < P15) { int d = id & 255; long k = id >> 8;
        wo1T[id] = W_o1[(size_t)d * 1024 + k]; return; }
}

// ---------------- generic bf16 MFMA GEMM ----------------
// MODE: 0 f32, 1 f16, 2 f32 exp, 4 fp8 exp
template<int BM, int BN, int NT, int MODE, bool BIAS, bool SWZ>
__global__ __launch_bounds__(NT)
void gemm_nt(const ushort* __restrict__ A, int lda, const ushort* __restrict__ Bm, int ldb,
             void* __restrict__ Cp, int ldc, const float* __restrict__ bias,
             int M, int N, int K)
{
    constexpr int WN = BN / 32;
    __shared__ ushort sA[BM * 32];
    __shared__ ushort sB[BN * 32];
    int tid = threadIdx.x, lane = tid & 63, wid = tid >> 6;
    int wm = wid / WN, wn = wid % WN;
    int mb = blockIdx.y, nb = blockIdx.x;
    if (SWZ) {
        int n = gridDim.x, x = nb & 7, y = nb >> 3, q = n >> 3, r = n & 7;
        nb = (x < r ? x * (q + 1) : r * (q + 1) + (x - r) * q) + y;
    }
    int l15 = lane & 15, lg = lane >> 4;
    f32x4 acc[2][2] = {};
    for (int k0 = 0; k0 < K; k0 += 32) {
        for (int idx = tid; idx < BM * 4; idx += NT) {
            int r = idx >> 2, kc = (idx & 3) << 3;
            int row = mb * BM + r;
            uint4 v = make_uint4(0u, 0u, 0u, 0u);
            if (row < M) v = *(const uint4*)(A + (size_t)row * lda + k0 + kc);
            *(uint4*)(&sA[r * 32 + kc]) = v;
        }
        for (int idx = tid; idx < BN * 4; idx += NT) {
            int r = idx >> 2, kc = (idx & 3) << 3;
            int row = nb * BN + r;
            uint4 v = make_uint4(0u, 0u, 0u, 0u);
            if (row < N) v = *(const uint4*)(Bm + (size_t)row * ldb + k0 + kc);
            *(uint4*)(&sB[r * 32 + kc]) = v;
        }
        __syncthreads();
        s16x8 a0 = *(const s16x8*)(&sA[(wm * 32 + l15) * 32 + lg * 8]);
        s16x8 a1 = *(const s16x8*)(&sA[(wm * 32 + 16 + l15) * 32 + lg * 8]);
        s16x8 b0 = *(const s16x8*)(&sB[(wn * 32 + l15) * 32 + lg * 8]);
        s16x8 b1 = *(const s16x8*)(&sB[(wn * 32 + 16 + l15) * 32 + lg * 8]);
        acc[0][0] = __builtin_amdgcn_mfma_f32_16x16x32_bf16(a0, b0, acc[0][0], 0, 0, 0);
        acc[0][1] = __builtin_amdgcn_mfma_f32_16x16x32_bf16(a0, b1, acc[0][1], 0, 0, 0);
        acc[1][0] = __builtin_amdgcn_mfma_f32_16x16x32_bf16(a1, b0, acc[1][0], 0, 0, 0);
        acc[1][1] = __builtin_amdgcn_mfma_f32_16x16x32_bf16(a1, b1, acc[1][1], 0, 0, 0);
        __syncthreads();
    }
    int cb = nb * BN + wn * 32, rb = mb * BM + wm * 32;
    #pragma unroll
    for (int mf = 0; mf < 2; ++mf)
    #pragma unroll
    for (int nf = 0; nf < 2; ++nf) {
        int col = cb + nf * 16 + l15;
        float bv = 0.f;
        if (BIAS) { if (col < N) bv = bias[col]; }
        #pragma unroll
        for (int r = 0; r < 4; ++r) {
            int row = rb + mf * 16 + lg * 4 + r;
            if (row < M && col < N) {
                float v = acc[mf][nf][r] + bv;
                if (MODE == 0)      ((float*)Cp)[(size_t)row * ldc + col] = v;
                else if (MODE == 1) ((ushort*)Cp)[(size_t)row * ldc + col] = __builtin_bit_cast(ushort, (_Float16)v);
                else if (MODE == 2) ((float*)Cp)[(size_t)row * ldc + col] = __expf(v);
                else                ((unsigned char*)Cp)[(size_t)row * ldc + col] = (unsigned char)f2e4(__expf(v));
            }
        }
    }
}

// ---------------- encoder (bank-padded, x reg-double-buffered) ----------------
__global__ __launch_bounds__(512, 2)
void enc_kernel(const ushort* __restrict__ xproj, const uint4* __restrict__ whh2,
                ushort* __restrict__ encoutB, float* __restrict__ hfin, float* __restrict__ cfin)
{
    __shared__ uint4  wlds[18 * 512];
    __shared__ __attribute__((aligned(16))) ushort hh16[2][2][136];
    int b = blockIdx.x & 31, dir = blockIdx.x >> 5;
    int t = threadIdx.x, j = t >> 1, kh = t & 1;
    const uint4* gw = whh2 + (size_t)dir * 64 * 512 + t;
    uint4 wreg[46];
    #pragma unroll
    for (int c = 0; c < 46; ++c) wreg[c] = gw[(size_t)c * 512];
    #pragma unroll
    for (int c = 46; c < 64; ++c) wlds[(c - 46) * 512 + t] = gw[(size_t)c * 512];
    if (t < 256) { hh16[0][t >> 7][t & 127] = 0; }
    float cst = 0.f, hst = 0.f;
    __syncthreads();
    const int khoff = kh * 512;
    // prefetch x for step 0
    ushort nxa, nxb;
    {
        int s0 = dir ? (S - 1) : 0;
        const ushort* xp = xproj + ((size_t)(s0 * B + b)) * 2048 + dir * 1024 + j + khoff;
        nxa = xp[0]; nxb = xp[256];
    }
    #pragma unroll 1
    for (int step = 0; step < S; ++step) {
        int cur = step & 1, nxt = cur ^ 1;
        int s = dir ? (S - 1 - step) : step;
        ushort xra = nxa, xrb = nxb;
        {   // issue next step's x loads now; consumed next iteration
            int stepn = (step + 1 < S) ? step + 1 : step;
            int sn = dir ? (S - 1 - stepn) : stepn;
            const ushort* xp = xproj + ((size_t)(sn * B + b)) * 2048 + dir * 1024 + j + khoff;
            nxa = xp[0]; nxb = xp[256];
        }
        float a0 = 0.f, a1 = 0.f, a2 = 0.f, a3 = 0.f;
        #pragma unroll
        for (int p = 0; p < 16; ++p) {
            uint4 hp = *(const uint4*)(&hh16[cur][kh][p * 8]);
            uint4 wi = wreg[p];
            uint4 wf = wreg[16 + p];
            uint4 wg = (p < 14) ? wreg[32 + p] : wlds[(p - 14) * 512 + t];
            uint4 wo = wlds[(p + 2) * 512 + t];
            h2f p0 = asH2(hp.x), p1 = asH2(hp.y), p2 = asH2(hp.z), p3 = asH2(hp.w);
            a0 = dot2(p0, asH2(wi.x), a0); a0 = dot2(p1, asH2(wi.y), a0);
            a0 = dot2(p2, asH2(wi.z), a0); a0 = dot2(p3, asH2(wi.w), a0);
            a1 = dot2(p0, asH2(wf.x), a1); a1 = dot2(p1, asH2(wf.y), a1);
            a1 = dot2(p2, asH2(wf.z), a1); a1 = dot2(p3, asH2(wf.w), a1);
            a2 = dot2(p0, asH2(wg.x), a2); a2 = dot2(p1, asH2(wg.y), a2);
            a2 = dot2(p2, asH2(wg.z), a2); a2 = dot2(p3, asH2(wg.w), a2);
            a3 = dot2(p0, asH2(wo.x), a3); a3 = dot2(p1, asH2(wo.y), a3);
            a3 = dot2(p2, asH2(wo.z), a3); a3 = dot2(p3, asH2(wo.w), a3);
        }
        float xv0 = (float)__builtin_bit_cast(_Float16, xra);
        float xv1 = (float)__builtin_bit_cast(_Float16, xrb);
        a0 += kh ? 0.f : xv0;  a1 += kh ? 0.f : xv1;
        a2 += kh ? xv0 : 0.f;  a3 += kh ? xv1 : 0.f;
        a0 += __shfl_xor(a0, 1); a1 += __shfl_xor(a1, 1);
        a2 += __shfl_xor(a2, 1); a3 += __shfl_xor(a3, 1);
        cst = sigmoidf_(a1) * cst + sigmoidf_(a0) * tanhf_(a2);
        hst = sigmoidf_(a3) * tanhf_(cst);
        if (kh == 0) {
            encoutB[((size_t)(b * S + s)) * 512 + dir * 256 + j] = f2bf(hst);
            hh16[nxt][j >> 7][j & 127] = __builtin_bit_cast(ushort, (_Float16)hst);
        }
        __syncthreads();
    }
    if (kh == 0) {
        hfin[(dir * 32 + b) * 256 + j] = hst;
        cfin[(dir * 32 + b) * 256 + j] = cst;
    }
}

// ---------------- decoder init ----------------
__global__ __launch_bounds__(256)
void initdec_kernel(const float* __restrict__ hfin, const float* __restrict__ cfin,
                    const float* __restrict__ wrhT, const float* __restrict__ b_rh,
                    const float* __restrict__ wrcT, const float* __restrict__ b_rc,
                    float* __restrict__ hPP, float* __restrict__ cPP, float* __restrict__ ctxPP)
{
    int b = blockIdx.x, j = threadIdx.x;
    float ah = b_rh[j], ac = b_rc[j];
    for (int k = 0; k < 512; ++k) {
        float hv = (k < 256) ? hfin[b * 256 + k] : hfin[(32 + b) * 256 + k - 256];
        float cv = (k < 256) ? cfin[b * 256 + k] : cfin[(32 + b) * 256 + k - 256];
        ah += hv * wrhT[k * 256 + j];
        ac += cv * wrcT[k * 256 + j];
    }
    hPP[b * 256 + j] = fmaxf(ah, 0.f);
    cPP[b * 256 + j] = fmaxf(ac, 0.f);
    ctxPP[b * 512 + j] = 0.f;
    ctxPP[b * 512 + 256 + j] = 0.f;
}

// ---------------- hid helper ----------------
DEV void hid_block(int idx, int tid, const float* hin, const float* cin, const float* ctxin,
                   const float* wo1T, const float* b_o1, ushort* hid_prev,
                   float xs[8][1024], float redh[4][8][64])
{
    int bg = idx >> 2, dg = idx & 3;
    for (int i = tid; i < 8192; i += 256) {
        int b8 = i >> 10, k = i & 1023;
        int b = bg * 8 + b8;
        float v;
        if (k < 256)      v = hin[b * 256 + k];
        else if (k < 512) v = cin[b * 256 + k - 256];
        else              v = ctxin[b * 512 + (k - 512)];
        xs[b8][k] = v;
    }
    __syncthreads();
    int dl = tid & 63, kq = tid >> 6;
    int d = dg * 64 + dl;
    float acc8[8] = {};
    for (int k = kq * 256; k < kq * 256 + 256; k += 4) {
        float w0 = wo1T[(size_t)k * 256 + d];
        float w1 = wo1T[(size_t)(k + 1) * 256 + d];
        float w2 = wo1T[(size_t)(k + 2) * 256 + d];
        float w3 = wo1T[(size_t)(k + 3) * 256 + d];
        #pragma unroll
        for (int b8 = 0; b8 < 8; ++b8) {
            float4 x = *(const float4*)(&xs[b8][k]);
            acc8[b8] += w0 * x.x + w1 * x.y + w2 * x.z + w3 * x.w;
        }
    }
    #pragma unroll
    for (int b8 = 0; b8 < 8; ++b8) redh[kq][b8][dl] = acc8[b8];
    __syncthreads();
    for (int i = tid; i < 512; i += 256) {
        int b8 = i >> 6, dl2 = i & 63;
        int d2 = dg * 64 + dl2;
        float v = redh[0][b8][dl2] + redh[1][b8][dl2] + redh[2][b8][dl2] + redh[3][b8][dl2] + b_o1[d2];
        hid_prev[(size_t)(bg * 8 + b8) * 256 + d2] = f2bf(v);
    }
}

// ---------------- K1: lstm (128) + hid(t-1) (16) ----------------
__global__ __launch_bounds__(256)
void dec_step1_kernel(const float* __restrict__ wcat, const float* __restrict__ bcv,
                      const float* __restrict__ ctxin,
                      const float* __restrict__ hin, const float* __restrict__ cin,
                      float* __restrict__ hout, float* __restrict__ cout,
                      const float* __restrict__ embt,
                      const float* __restrict__ wo1T, const float* __restrict__ b_o1,
                      ushort* __restrict__ hid_prev, int havePrev)
{
    __shared__ float pre[256];
    __shared__ float xs[8][1024];
    __shared__ float redh[4][8][64];
    int blk = blockIdx.x, tid = threadIdx.x;
    if (blk < 128) {
        int b = tid & 31, ci = tid >> 5;
        int gi = ci >> 1, jj = ci & 1;
        int j = (blk << 1) + jj;
        int col = gi * 256 + j;
        float acc = bcv[col];
        const float4* w = (const float4*)(wcat + (size_t)col * 896);
        const float4* x0 = (const float4*)(ctxin + b * 512);
        #pragma unroll 8
        for (int u = 0; u < 128; ++u) { float4 a = w[u], q = x0[u]; acc += a.x*q.x + a.y*q.y + a.z*q.z + a.w*q.w; }
        const float4* x1 = (const float4*)(embt + b * 128);
        #pragma unroll 8
        for (int u = 0; u < 32; ++u) { float4 a = w[128 + u], q = x1[u]; acc += a.x*q.x + a.y*q.y + a.z*q.z + a.w*q.w; }
        const float4* x2 = (const float4*)(hin + b * 256);
        #pragma unroll 8
        for (int u = 0; u < 64; ++u) { float4 a = w[160 + u], q = x2[u]; acc += a.x*q.x + a.y*q.y + a.z*q.z + a.w*q.w; }
        pre[tid] = acc;
        __syncthreads();
        if (tid < 64) {
            int b2 = tid & 31, qq = tid >> 5;
            int j2 = (blk << 1) + qq;
            float iv = pre[(0 + qq) * 32 + b2];
            float fv = pre[(2 + qq) * 32 + b2];
            float gv = pre[(4 + qq) * 32 + b2];
            float ov = pre[(6 + qq) * 32 + b2];
            float cp = cin[b2 * 256 + j2];
            float cn = sigmoidf_(fv) * cp + sigmoidf_(iv) * tanhf_(gv);
            float hn = sigmoidf_(ov) * tanhf_(cn);
            cout[b2 * 256 + j2] = cn;
            hout[b2 * 256 + j2] = hn;
        }
    } else {
        if (!havePrev) return;
        hid_block(blk - 128, tid, hin, cin, ctxin, wo1T, b_o1, hid_prev, xs, redh);
    }
}

// ---------------- tail: hid for t = T-1 ----------------
__global__ __launch_bounds__(256)
void dec_tail_kernel(const float* __restrict__ hin, const float* __restrict__ cin,
                     const float* __restrict__ ctxin,
                     const float* __restrict__ wo1T, const float* __restrict__ b_o1,
                     ushort* __restrict__ hid_prev)
{
    __shared__ float xs[8][1024];
    __shared__ float redh[4][8][64];
    hid_block(blockIdx.x, threadIdx.x, hin, cin, ctxin, wo1T, b_o1, hid_prev, xs, redh);
}

// ---------------- K3: fused per-b attention (daf, e, softmax, atts, ctx, pgen) ----------------
__global__ __launch_bounds__(512)
void dec_attn_kernel(const float* __restrict__ h, const float* __restrict__ c,
                     const ushort* __restrict__ wafbf, const float* __restrict__ b_af,
                     const ushort* __restrict__ encfeatB, const float* __restrict__ wv,
                     const int* __restrict__ inputs, const ushort* __restrict__ encoutB,
                     const float* __restrict__ ctxold, float* __restrict__ ctxnew,
                     const float* __restrict__ embt, const float* __restrict__ wz,
                     const float* __restrict__ cpgp,
                     float* __restrict__ pgen_t, float* __restrict__ atts_t)
{
    __shared__ float hc[512];
    __shared__ float dafL[512];
    __shared__ float scL[400];
    __shared__ float redn[512];
    __shared__ float part8[8][512];
    __shared__ float ctxL[512];
    int b = blockIdx.x, tid = threadIdx.x;
    hc[tid] = (tid < 256) ? h[b * 256 + tid] : c[b * 256 + tid - 256];
    __syncthreads();
    // P1: daf[d] (d = tid), W_af bf16 [k][d] coalesced
    {
        float p0 = 0.f, p1 = 0.f, p2 = 0.f, p3 = 0.f;
        const ushort* wcol = wafbf + tid;
        #pragma unroll 4
        for (int k = 0; k < 512; k += 4) {
            p0 += hc[k]     * bf2f(wcol[(size_t)k * 512]);
            p1 += hc[k + 1] * bf2f(wcol[(size_t)(k + 1) * 512]);
            p2 += hc[k + 2] * bf2f(wcol[(size_t)(k + 2) * 512]);
            p3 += hc[k + 3] * bf2f(wcol[(size_t)(k + 3) * 512]);
        }
        dafL[tid] = b_af[tid] + ((p0 + p1) + (p2 + p3));
    }
    __syncthreads();
    int sl = tid >> 6, dth = tid & 63;
    // preload daf & wv slices into regs (avoids strided-LDS bank conflicts in s-loop)
    float dreg[8], wreg[8];
    #pragma unroll
    for (int jj = 0; jj < 8; ++jj) { dreg[jj] = dafL[dth * 8 + jj]; wreg[jj] = wv[dth * 8 + jj]; }
    // P2: e[s] -> exp (wave sl handles s = sl + 8i)
    for (int i = 0; i < 50; ++i) {
        int s = sl + i * 8;
        uint4 u = *(const uint4*)(encfeatB + ((size_t)b * S + s) * 512 + dth * 8);
        h2f e0 = asH2(u.x), e1 = asH2(u.y), e2 = asH2(u.z), e3 = asH2(u.w);
        float e = tanhf_((float)e0.x + dreg[0]) * wreg[0] + tanhf_((float)e0.y + dreg[1]) * wreg[1]
                + tanhf_((float)e1.x + dreg[2]) * wreg[2] + tanhf_((float)e1.y + dreg[3]) * wreg[3]
                + tanhf_((float)e2.x + dreg[4]) * wreg[4] + tanhf_((float)e2.y + dreg[5]) * wreg[5]
                + tanhf_((float)e3.x + dreg[6]) * wreg[6] + tanhf_((float)e3.y + dreg[7]) * wreg[7];
        e += __shfl_xor(e, 1);  e += __shfl_xor(e, 2);
        e += __shfl_xor(e, 4);  e += __shfl_xor(e, 8);
        e += __shfl_xor(e, 16); e += __shfl_xor(e, 32);
        if (dth == 0) {
            float m = (inputs[s * 32 + b] != 0) ? 1.f : 0.f;
            scL[s] = m * __expf(e);
        }
    }
    __syncthreads();
    // P3: softmax denom
    redn[tid] = (tid < 400) ? scL[tid] : 0.f;
    __syncthreads();
    for (int o = 256; o > 0; o >>= 1) { if (tid < o) redn[tid] += redn[tid + o]; __syncthreads(); }
    float rinv = 1.f / redn[0];
    if (tid < 400) atts_t[tid * 32 + b] = scL[tid] * rinv;
    // P4: ctx partials (unnormalized; scale by rinv at reduce)
    {
        float acc8[8] = {};
        for (int i = 0; i < 50; ++i) {
            int s = sl + i * 8;
            float a = scL[s];
            uint4 u = *(const uint4*)(encoutB + ((size_t)b * S + s) * 512 + dth * 8);
            acc8[0] += a * bf2f(u.x & 0xffffu);
            acc8[1] += a * bf2f(u.x >> 16);
            acc8[2] += a * bf2f(u.y & 0xffffu);
            acc8[3] += a * bf2f(u.y >> 16);
            acc8[4] += a * bf2f(u.z & 0xffffu);
            acc8[5] += a * bf2f(u.z >> 16);
            acc8[6] += a * bf2f(u.w & 0xffffu);
            acc8[7] += a * bf2f(u.w >> 16);
        }
        #pragma unroll
        for (int jj = 0; jj < 8; ++jj) part8[sl][dth * 8 + jj] = acc8[jj];
    }
    __syncthreads();
    {
        float v = 0.f;
        #pragma unroll
        for (int s8 = 0; s8 < 8; ++s8) v += part8[s8][tid];
        v *= rinv;
        ctxL[tid] = v;
        ctxnew[(size_t)b * 512 + tid] = v;
    }
    __syncthreads();
    // P5: pgen = sigmoid(wz . [ctx_t; h; c; ctx_{t-1}; emb_t] + cpgp)
    {
        float pp = 0.f;
        for (int k = tid; k < 1664; k += 512) {
            float zv;
            if (k < 512)        zv = ctxL[k];
            else if (k < 1024)  zv = hc[k - 512];
            else if (k < 1536)  zv = ctxold[(size_t)b * 512 + (k - 1024)];
            else                zv = embt[b * 128 + (k - 1536)];
            pp += wz[k] * zv;
        }
        redn[tid] = pp;
        __syncthreads();
        for (int o = 256; o > 0; o >>= 1) { if (tid < o) redn[tid] += redn[tid + o]; __syncthreads(); }
        if (tid == 0) pgen_t[b] = sigmoidf_(redn[0] + cpgp[0]);
    }
}

// ---------------- batched out: fp8 row-sum, scale+write, scatter ----------------
__global__ __launch_bounds__(256)
void dec_out2_kernel(const unsigned char* __restrict__ pbuf, const float* __restrict__ pgenAll,
                     const int* __restrict__ tex, const float* __restrict__ attsAll,
                     float* __restrict__ outsAll)
{
    int tb = blockIdx.x, t = threadIdx.x;
    int tstep = tb >> 5, b = tb & 31;
    const unsigned char* prow = pbuf + (size_t)tb * VP;
    float part = 0.f;
    for (int i = t; i < V / 8; i += 256) {
        uint2 u = *(const uint2*)(prow + i * 8);
        unsigned w0 = u.x, w1 = u.y;
        part += e42f(w0 & 255) + e42f((w0 >> 8) & 255) + e42f((w0 >> 16) & 255) + e42f(w0 >> 24);
        part += e42f(w1 & 255) + e42f((w1 >> 8) & 255) + e42f((w1 >> 16) & 255) + e42f(w1 >> 24);
    }
    __shared__ float red[256];
    red[t] = part;
    __syncthreads();
    for (int o = 128; o > 0; o >>= 1) { if (t < o) red[t] += red[t + o]; __syncthreads(); }
    float pg = pgenAll[tb];
    float sca = pg / red[0];
    float om = 1.f - pg;
    float* orow = outsAll + (size_t)tstep * B * VO + (size_t)b * VO;
    for (int i = t; i < V / 8; i += 256) {
        uint2 u = *(const uint2*)(prow + i * 8);
        unsigned w0 = u.x, w1 = u.y;
        float2* o2 = (float2*)(orow + i * 8);
        o2[0] = make_float2(e42f(w0 & 255) * sca, e42f((w0 >> 8) & 255) * sca);
        o2[1] = make_float2(e42f((w0 >> 16) & 255) * sca, e42f(w0 >> 24) * sca);
        o2[2] = make_float2(e42f(w1 & 255) * sca, e42f((w1 >> 8) & 255) * sca);
        o2[3] = make_float2(e42f((w1 >> 16) & 255) * sca, e42f(w1 >> 24) * sca);
    }
    if (t < OOV) orow[V + t] = 0.f;
    __syncthreads();
    const float* attst = attsAll + (size_t)tstep * SB;
    for (int si = t; si < 400; si += 256)
        atomicAdd(orow + tex[si * 32 + b], om * attst[si * 32 + b]);
}

// ---------------- host ----------------
extern "C" void kernel_launch(void* const* d_in, const int* in_sizes, int n_in,
                              void* d_out, int out_size, void* d_ws, size_t ws_size,
                              hipStream_t stream)
{
    const int*   inputs  = (const int*)d_in[0];
    const int*   toksAll = (const int*)d_in[2];
    const int*   tex     = (const int*)d_in[3];
    const float* emb     = (const float*)d_in[5];
    const float* Wih_f   = (const float*)d_in[6];
    const float* Whh_f   = (const float*)d_in[7];
    const float* bih_f   = (const float*)d_in[8];
    const float* bhh_f   = (const float*)d_in[9];
    const float* Wih_b   = (const float*)d_in[10];
    const float* Whh_b   = (const float*)d_in[11];
    const float* bih_b   = (const float*)d_in[12];
    const float* bhh_b   = (const float*)d_in[13];
    const float* W_feat  = (const float*)d_in[14];
    const float* W_rh    = (const float*)d_in[15];
    const float* b_rh    = (const float*)d_in[16];
    const float* W_rc    = (const float*)d_in[17];
    const float* b_rc    = (const float*)d_in[18];
    const float* W_af    = (const float*)d_in[19];
    const float* b_af    = (const float*)d_in[20];
    const float* w_v     = (const float*)d_in[21];
    const float* W_ctx   = (const float*)d_in[22];
    const float* b_ctx   = (const float*)d_in[23];
    const float* dWih    = (const float*)d_in[24];
    const float* dWhh    = (const float*)d_in[25];
    const float* dbih    = (const float*)d_in[26];
    const float* dbhh    = (const float*)d_in[27];
    const float* W_pg    = (const float*)d_in[28];
    const float* b_pg    = (const float*)d_in[29];
    const float* W_o1    = (const float*)d_in[30];
    const float* b_o1    = (const float*)d_in[31];
    const float* W_o2    = (const float*)d_in[32];
    const float* b_o2    = (const float*)d_in[33];

    char* wsb = (char*)d_ws;
    ushort*   emb2d   = (ushort*)(wsb + OFF_EMB2D);
    ushort*   wihcat  = (ushort*)(wsb + OFF_WIHCAT);
    float*    biasx   = (float*)(wsb + OFF_BIASX);
    ushort*   wfeatbf = (ushort*)(wsb + OFF_WFEAT);
    ushort*   wo2bf   = (ushort*)(wsb + OFF_WO2);
    unsigned* whh2    = (unsigned*)(wsb + OFF_WHH2);
    float*    wcat    = (float*)(wsb + OFF_WCAT);
    float*    bcv     = (float*)(wsb + OFF_BC);
    float*    cpgp    = (float*)(wsb + OFF_CPG);
    float*    wrhT    = (float*)(wsb + OFF_WRHT);
    float*    wrcT    = (float*)(wsb + OFF_WRCT);
    float*    embdec  = (float*)(wsb + OFF_EMBDEC);
    float*    wz      = (float*)(wsb + OFF_WZ);
    ushort*   wafbf   = (ushort*)(wsb + OFF_WAFT);
    float*    wo1T    = (float*)(wsb + OFF_WO1T);
    ushort*   xproj   = (ushort*)(wsb + OFF_XPROJ);
    ushort*   encoutB = (ushort*)(wsb + OFF_ENCOUT);
    ushort*   encfeatB= (ushort*)(wsb + OFF_ENCFEAT);
    float*    hfin    = (float*)(wsb + OFF_HFIN);
    float*    cfin    = (float*)(wsb + OFF_CFIN);
    float*    hPP     = (float*)(wsb + OFF_HPP);
    float*    cPP     = (float*)(wsb + OFF_CPP);
    float*    ctxPP   = (float*)(wsb + OFF_CTXPP);
    float*    pgenAll = (float*)(wsb + OFF_PGEN);
    ushort*   hidAll  = (ushort*)(wsb + OFF_HIDALL);
    unsigned char* pbuf = (unsigned char*)(wsb + OFF_PBUF);

    float* outs = (float*)d_out;
    float* atts = outs + (size_t)T * B * VO;

    int prep_blocks = (int)((PREP_TOTAL + 255) / 256);
    prep_kernel<<<prep_blocks, 256, 0, stream>>>(
        Wih_f, Wih_b, bih_f, bhh_f, bih_b, bhh_b, W_feat, W_o2, Whh_f, Whh_b,
        dWih, W_ctx, W_pg, b_pg, b_ctx, dbih, dbhh, emb, inputs, dWhh, W_rh, W_rc,
        toksAll, W_af, W_o1,
        emb2d, wihcat, biasx, wfeatbf, wo2bf, whh2, wcat, cpgp, bcv, wrhT, wrcT,
        embdec, wz, wafbf, wo1T);

    gemm_nt<64, 64, 256, 1, true, false><<<dim3(2048 / 64, SB / 64), 256, 0, stream>>>(
        emb2d, 128, wihcat, 128, (void*)xproj, 2048, biasx, SB, 2048, 128);

    enc_kernel<<<64, 512, 0, stream>>>(xproj, (const uint4*)whh2, encoutB, hfin, cfin);

    initdec_kernel<<<32, 256, 0, stream>>>(hfin, cfin, wrhT, b_rh, wrcT, b_rc, hPP, cPP, ctxPP);

    gemm_nt<64, 64, 256, 1, false, false><<<dim3(512 / 64, SB / 64), 256, 0, stream>>>(
        encoutB, 512, wfeatbf, 512, (void*)encfeatB, 512, nullptr, SB, 512, 512);

    for (int t = 0; t < T; ++t) {
        int p = t & 1, q = p ^ 1;
        float* ctxin = ctxPP + (size_t)p * 16384;
        float* hin = hPP + (size_t)p * 8192;
        float* cin = cPP + (size_t)p * 8192;
        float* hout = hPP + (size_t)q * 8192;
        float* cout = cPP + (size_t)q * 8192;
        const float* embt = embdec + (size_t)t * 4096;
        ushort* hid_prev = (t > 0) ? hidAll + (size_t)(t - 1) * 8192 : hidAll;

        dec_step1_kernel<<<144, 256, 0, stream>>>(wcat, bcv, ctxin, hin, cin,
                                                  hout, cout, embt, wo1T, b_o1,
                                                  hid_prev, t > 0 ? 1 : 0);
        dec_attn_kernel<<<32, 512, 0, stream>>>(hout, cout, wafbf, b_af, encfeatB, w_v,
                                                inputs, encoutB,
                                                ctxin, ctxPP + (size_t)q * 16384,
                                                embt, wz, cpgp,
                                                pgenAll + (size_t)t * 32,
                                                atts + (size_t)t * SB);
    }
    // tail: hid for t = T-1 (states + ctx_{T-1} in slot 0 after t=31)
    dec_tail_kernel<<<16, 256, 0, stream>>>(hPP, cPP, ctxPP, wo1T, b_o1,
                                            hidAll + (size_t)(T - 1) * 8192);

    gemm_nt<64, 128, 512, 4, true, true><<<dim3(391, 16), 512, 0, stream>>>(
        hidAll, 256, wo2bf, 256, (void*)pbuf, VP, b_o2, T * B, V, 256);
    dec_out2_kernel<<<T * B, 256, 0, stream>>>(pbuf, pgenAll, tex, atts, outs);
}

// Round 8
// 4273.641 us; speedup vs baseline: 4.2884x; 1.0566x over previous
//
#include <hip/hip_runtime.h>

#define DEV static __device__ __forceinline__

typedef short  s16x8 __attribute__((ext_vector_type(8)));
typedef float  f32x4 __attribute__((ext_vector_type(4)));
typedef _Float16 h2f __attribute__((ext_vector_type(2)));

constexpr int S = 400, B = 32, T = 32, V = 50000, OOV = 50, E = 128, H = 256;
constexpr int VO = V + OOV, SB = S * B;
constexpr int VP = 50048;           // fp8 pbuf row stride

DEV ushort f2bf(float x) {
    union { float f; unsigned u; } a; a.f = x;
    unsigned r = (a.u + 0x7fffu + ((a.u >> 16) & 1u)) >> 16;
    return (ushort)r;
}
DEV float bf2f(unsigned b) {
    union { unsigned u; float f; } a; a.u = b << 16; return a.f;
}
DEV float sigmoidf_(float x) { return 1.0f / (1.0f + __expf(-x)); }
DEV float tanhf_(float x) { float e = __expf(2.0f * x); return 1.0f - 2.0f / (e + 1.0f); }
DEV h2f asH2(unsigned u) { union { unsigned u; h2f h; } x; x.u = u; return x.h; }

#if __has_builtin(__builtin_amdgcn_fdot2)
DEV float dot2(h2f a, h2f b, float c) { return __builtin_amdgcn_fdot2(a, b, c, false); }
#else
DEV float dot2(h2f a, h2f b, float c) { return c + (float)a.x * (float)b.x + (float)a.y * (float)b.y; }
#endif

// fp8 e4m3 manual encode/decode (positive values only: exp of logits)
DEV unsigned f2e4(float v) {
    union { float f; unsigned u; } a; a.f = v;
    unsigned u = a.u + 0x0007FFFFu + ((a.u >> 20) & 1u);
    int e = (int)((u >> 23) & 255) - 127 + 7;
    unsigned m = (u >> 20) & 7u;
    if (e <= 0) return 0u;
    if (e > 15) { e = 15; m = 6; }
    return (unsigned)((e << 3) | m);
}
DEV float e42f(unsigned b) {
    int e = (int)((b >> 3) & 15), m = (int)(b & 7);
    if (e == 0) return (float)m * 1.953125e-3f;
    union { unsigned u; float f; } a;
    a.u = ((unsigned)(e + 120) << 23) | ((unsigned)m << 20);
    return a.f;
}

// ---------------- workspace layout ----------------
constexpr size_t SZ_EMB2D  = (size_t)SB * E * 2;
constexpr size_t SZ_WIHCAT = (size_t)2048 * 128 * 2;
constexpr size_t SZ_BIASX  = 2048 * 4;
constexpr size_t SZ_WFEAT  = (size_t)512 * 512 * 2;
constexpr size_t SZ_WO2    = (size_t)V * H * 2;
constexpr size_t SZ_WHH2   = (size_t)2 * 64 * 512 * 16;
constexpr size_t SZ_WCAT   = (size_t)1024 * 896 * 4;
constexpr size_t SZ_BC     = 1024 * 4;
constexpr size_t SZ_CPG    = 256;
constexpr size_t SZ_WRHT   = (size_t)512 * 256 * 4;
constexpr size_t SZ_WRCT   = (size_t)512 * 256 * 4;
constexpr size_t SZ_EMBDEC = (size_t)T * B * E * 4;
constexpr size_t SZ_WZ     = 1664 * 4 + 256;
constexpr size_t SZ_WAFT   = (size_t)512 * 512 * 4;    // holds bf16 wafbf (first 512KB)
constexpr size_t SZ_WO1T   = (size_t)1024 * 256 * 4;   // [k][d] f32
constexpr size_t SZ_XPROJ  = (size_t)SB * 2048 * 2;    // aliased by fp8 pbuf later
constexpr size_t SZ_ENCOUT = (size_t)SB * 512 * 2;     // b-major bf16
constexpr size_t SZ_ENCFEAT= (size_t)SB * 512 * 2;     // b-major f16
constexpr size_t SZ_HFIN   = (size_t)2 * B * H * 4;
constexpr size_t SZ_HPP    = (size_t)2 * B * H * 4;
constexpr size_t SZ_CTXPP  = (size_t)2 * B * 512 * 4;
constexpr size_t SZ_DAF    = (size_t)B * 512 * 4;
constexpr size_t SZ_EXPS   = (size_t)SB * 4;
constexpr size_t SZ_PGEN   = (size_t)T * B * 4;
constexpr size_t SZ_HIDALL = (size_t)T * B * 256 * 2;

constexpr size_t OFF_EMB2D  = 0;
constexpr size_t OFF_WIHCAT = OFF_EMB2D  + SZ_EMB2D;
constexpr size_t OFF_BIASX  = OFF_WIHCAT + SZ_WIHCAT;
constexpr size_t OFF_WFEAT  = OFF_BIASX  + SZ_BIASX;
constexpr size_t OFF_WO2    = OFF_WFEAT  + SZ_WFEAT;
constexpr size_t OFF_WHH2   = OFF_WO2    + SZ_WO2;
constexpr size_t OFF_WCAT   = OFF_WHH2   + SZ_WHH2;
constexpr size_t OFF_BC     = OFF_WCAT   + SZ_WCAT;
constexpr size_t OFF_CPG    = OFF_BC     + SZ_BC;
constexpr size_t OFF_WRHT   = OFF_CPG    + SZ_CPG;
constexpr size_t OFF_WRCT   = OFF_WRHT   + SZ_WRHT;
constexpr size_t OFF_EMBDEC = OFF_WRCT   + SZ_WRCT;
constexpr size_t OFF_WZ     = OFF_EMBDEC + SZ_EMBDEC;
constexpr size_t OFF_WAFT   = OFF_WZ     + SZ_WZ;
constexpr size_t OFF_WO1T   = OFF_WAFT   + SZ_WAFT;
constexpr size_t OFF_XPROJ  = OFF_WO1T   + SZ_WO1T;
constexpr size_t OFF_ENCOUT = OFF_XPROJ  + SZ_XPROJ;
constexpr size_t OFF_ENCFEAT= OFF_ENCOUT + SZ_ENCOUT;
constexpr size_t OFF_HFIN   = OFF_ENCFEAT+ SZ_ENCFEAT;
constexpr size_t OFF_CFIN   = OFF_HFIN   + SZ_HFIN;
constexpr size_t OFF_HPP    = OFF_CFIN   + SZ_HFIN;
constexpr size_t OFF_CPP    = OFF_HPP    + SZ_HPP;
constexpr size_t OFF_CTXPP  = OFF_CPP    + SZ_HPP;
constexpr size_t OFF_DAF    = OFF_CTXPP  + SZ_CTXPP;
constexpr size_t OFF_EXPS   = OFF_DAF    + SZ_DAF;
constexpr size_t OFF_PGEN   = OFF_EXPS   + SZ_EXPS;
constexpr size_t OFF_HIDALL = OFF_PGEN   + SZ_PGEN;
constexpr size_t OFF_PBUF   = OFF_XPROJ;   // xproj dead after encoder

// ---------------- prep ----------------
constexpr long P1 = 2048L*128;     // wihcat bf16
constexpr long P2 = 2048;          // biasx
constexpr long P3 = 512L*512;      // wfeat bf16
constexpr long P4 = (long)V*H;     // wo2 bf16
constexpr long P5 = 2L*64*512*4;   // whh2 dwords
constexpr long P6 = 1024L*896;     // wcat f32
constexpr long P7 = 1;             // cpg
constexpr long P8 = 1024;          // bcv
constexpr long P9 = (long)SB*E;    // emb2d
constexpr long P10 = 512L*256;     // wrhT
constexpr long P11 = 512L*256;     // wrcT
constexpr long P12 = 32L*32*128;   // embdec
constexpr long P13 = 1664;         // wz
constexpr long P14 = 512L*512;     // wafbf (bf16, [k][d])
constexpr long P15 = 1024L*256;    // wo1T
constexpr long PREP_TOTAL = P1+P2+P3+P4+P5+P6+P7+P8+P9+P10+P11+P12+P13+P14+P15;

__global__ __launch_bounds__(256)
void prep_kernel(const float* __restrict__ Wih_f, const float* __restrict__ Wih_b,
                 const float* __restrict__ bih_f, const float* __restrict__ bhh_f,
                 const float* __restrict__ bih_b, const float* __restrict__ bhh_b,
                 const float* __restrict__ W_feat, const float* __restrict__ W_o2,
                 const float* __restrict__ Whh_f, const float* __restrict__ Whh_b,
                 const float* __restrict__ dWih, const float* __restrict__ W_ctx,
                 const float* __restrict__ W_pg, const float* __restrict__ b_pg,
                 const float* __restrict__ b_ctx, const float* __restrict__ dbih,
                 const float* __restrict__ dbhh, const float* __restrict__ emb,
                 const int* __restrict__ inputs, const float* __restrict__ dWhh,
                 const float* __restrict__ W_rh, const float* __restrict__ W_rc,
                 const int* __restrict__ toks, const float* __restrict__ W_af,
                 const float* __restrict__ W_o1,
                 ushort* __restrict__ emb2d, ushort* __restrict__ wihcat,
                 float* __restrict__ biasx, ushort* __restrict__ wfeatbf,
                 ushort* __restrict__ wo2bf, unsigned* __restrict__ whh2,
                 float* __restrict__ wcat, float* __restrict__ cpgp,
                 float* __restrict__ bcv, float* __restrict__ wrhT,
                 float* __restrict__ wrcT, float* __restrict__ embdec,
                 float* __restrict__ wz, ushort* __restrict__ wafbf,
                 float* __restrict__ wo1T)
{
    long id = (long)blockIdx.x * 256 + threadIdx.x;
    if (id < P1) { int r = id >> 7, e = id & 127;
        float v = (r < 1024) ? Wih_f[r*128+e] : Wih_b[(r-1024)*128+e];
        wihcat[id] = f2bf(v); return; }
    id -= P1;
    if (id < P2) { biasx[id] = (id < 1024) ? bih_f[id]+bhh_f[id] : bih_b[id-1024]+bhh_b[id-1024]; return; }
    id -= P2;
    if (id < P3) { wfeatbf[id] = f2bf(W_feat[id]); return; }
    id -= P3;
    if (id < P4) { wo2bf[id] = f2bf(W_o2[id]); return; }
    id -= P4;
    if (id < P5) {
        int q = id & 3; long r = id >> 2;
        int t = (int)(r & 511); r >>= 9; int c = (int)(r & 63); int dir = (int)(r >> 6);
        int gate = c >> 4, p = c & 15, kh = t & 1;
        int j = t >> 1;
        int k0 = kh * 128 + p * 8 + 2 * q;
        int row = gate * 256 + j;
        const float* W = dir ? Whh_b : Whh_f;
        h2f hv; hv.x = (_Float16)W[(size_t)row*256 + k0]; hv.y = (_Float16)W[(size_t)row*256 + k0 + 1];
        whh2[id] = __builtin_bit_cast(unsigned, hv); return; }
    id -= P5;
    if (id < P6) { int col = (int)(id / 896), k = (int)(id % 896);
        if (k < 640) {
            float acc = 0.f;
            for (int e = 0; e < 128; ++e) acc += dWih[col*128+e] * W_ctx[e*640+k];
            wcat[id] = acc;
        } else wcat[id] = dWhh[(size_t)col*256 + (k - 640)];
        return; }
    id -= P6;
    if (id < P7) { float acc = b_pg[0];
        for (int e = 0; e < 128; ++e) acc += W_pg[1024+e] * b_ctx[e];
        cpgp[0] = acc; return; }
    id -= P7;
    if (id < P8) { float acc = dbih[id] + dbhh[id];
        for (int e = 0; e < 128; ++e) acc += dWih[id*128+e] * b_ctx[e];
        bcv[id] = acc; return; }
    id -= P8;
    if (id < P9) { long sb = id >> 7; int e = id & 127;
        emb2d[id] = f2bf(emb[(size_t)inputs[sb]*128 + e]); return; }
    id -= P9;
    if (id < P10) { int j = id & 255; long k = id >> 8;
        wrhT[id] = W_rh[(size_t)j * 512 + k]; return; }
    id -= P10;
    if (id < P11) { int j = id & 255; long k = id >> 8;
        wrcT[id] = W_rc[(size_t)j * 512 + k]; return; }
    id -= P11;
    if (id < P12) { long tb = id >> 7; int e = id & 127;
        embdec[id] = emb[(size_t)toks[tb]*128 + e]; return; }
    id -= P12;
    if (id < P13) {
        int k = (int)id;
        if (k < 1024) wz[k] = W_pg[k];
        else { int u = k - 1024; float acc = 0.f;
            for (int e = 0; e < 128; ++e) acc += W_pg[1024+e] * W_ctx[e*640+u];
            wz[k] = acc; }
        return; }
    id -= P13;
    if (id < P14) { int d = id & 511; long k = id >> 9;   // wafbf[k][d]
        wafbf[id] = f2bf(W_af[(size_t)d * 512 + k]); return; }
    id -= P14;
    if (id < P15) { int d = id & 255; long k = id >> 8;
        wo1T[id] = W_o1[(size_t)d * 1024 + k]; return; }
}

// ---------------- generic bf16 MFMA GEMM ----------------
// MODE: 0 f32, 1 f16, 2 f32 exp, 4 fp8 exp
template<int BM, int BN, int NT, int MODE, bool BIAS, bool SWZ>
__global__ __launch_bounds__(NT)
void gemm_nt(const ushort* __restrict__ A, int lda, const ushort* __restrict__ Bm, int ldb,
             void* __restrict__ Cp, int ldc, const float* __restrict__ bias,
             int M, int N, int K)
{
    constexpr int WN = BN / 32;
    __shared__ ushort sA[BM * 32];
    __shared__ ushort sB[BN * 32];
    int tid = threadIdx.x, lane = tid & 63, wid = tid >> 6;
    int wm = wid / WN, wn = wid % WN;
    int mb = blockIdx.y, nb = blockIdx.x;
    if (SWZ) {
        int n = gridDim.x, x = nb & 7, y = nb >> 3, q = n >> 3, r = n & 7;
        nb = (x < r ? x * (q + 1) : r * (q + 1) + (x - r) * q) + y;
    }
    int l15 = lane & 15, lg = lane >> 4;
    f32x4 acc[2][2] = {};
    for (int k0 = 0; k0 < K; k0 += 32) {
        for (int idx = tid; idx < BM * 4; idx += NT) {
            int r = idx >> 2, kc = (idx & 3) << 3;
            int row = mb * BM + r;
            uint4 v = make_uint4(0u, 0u, 0u, 0u);
            if (row < M) v = *(const uint4*)(A + (size_t)row * lda + k0 + kc);
            *(uint4*)(&sA[r * 32 + kc]) = v;
        }
        for (int idx = tid; idx < BN * 4; idx += NT) {
            int r = idx >> 2, kc = (idx & 3) << 3;
            int row = nb * BN + r;
            uint4 v = make_uint4(0u, 0u, 0u, 0u);
            if (row < N) v = *(const uint4*)(Bm + (size_t)row * ldb + k0 + kc);
            *(uint4*)(&sB[r * 32 + kc]) = v;
        }
        __syncthreads();
        s16x8 a0 = *(const s16x8*)(&sA[(wm * 32 + l15) * 32 + lg * 8]);
        s16x8 a1 = *(const s16x8*)(&sA[(wm * 32 + 16 + l15) * 32 + lg * 8]);
        s16x8 b0 = *(const s16x8*)(&sB[(wn * 32 + l15) * 32 + lg * 8]);
        s16x8 b1 = *(const s16x8*)(&sB[(wn * 32 + 16 + l15) * 32 + lg * 8]);
        acc[0][0] = __builtin_amdgcn_mfma_f32_16x16x32_bf16(a0, b0, acc[0][0], 0, 0, 0);
        acc[0][1] = __builtin_amdgcn_mfma_f32_16x16x32_bf16(a0, b1, acc[0][1], 0, 0, 0);
        acc[1][0] = __builtin_amdgcn_mfma_f32_16x16x32_bf16(a1, b0, acc[1][0], 0, 0, 0);
        acc[1][1] = __builtin_amdgcn_mfma_f32_16x16x32_bf16(a1, b1, acc[1][1], 0, 0, 0);
        __syncthreads();
    }
    int cb = nb * BN + wn * 32, rb = mb * BM + wm * 32;
    #pragma unroll
    for (int mf = 0; mf < 2; ++mf)
    #pragma unroll
    for (int nf = 0; nf < 2; ++nf) {
        int col = cb + nf * 16 + l15;
        float bv = 0.f;
        if (BIAS) { if (col < N) bv = bias[col]; }
        #pragma unroll
        for (int r = 0; r < 4; ++r) {
            int row = rb + mf * 16 + lg * 4 + r;
            if (row < M && col < N) {
                float v = acc[mf][nf][r] + bv;
                if (MODE == 0)      ((float*)Cp)[(size_t)row * ldc + col] = v;
                else if (MODE == 1) ((ushort*)Cp)[(size_t)row * ldc + col] = __builtin_bit_cast(ushort, (_Float16)v);
                else if (MODE == 2) ((float*)Cp)[(size_t)row * ldc + col] = __expf(v);
                else                ((unsigned char*)Cp)[(size_t)row * ldc + col] = (unsigned char)f2e4(__expf(v));
            }
        }
    }
}

// ---------------- encoder (bank-padded, round-5 body) ----------------
__global__ __launch_bounds__(512, 2)
void enc_kernel(const ushort* __restrict__ xproj, const uint4* __restrict__ whh2,
                ushort* __restrict__ encoutB, float* __restrict__ hfin, float* __restrict__ cfin)
{
    __shared__ uint4  wlds[18 * 512];
    __shared__ __attribute__((aligned(16))) ushort hh16[2][2][136];
    int b = blockIdx.x & 31, dir = blockIdx.x >> 5;
    int t = threadIdx.x, j = t >> 1, kh = t & 1;
    const uint4* gw = whh2 + (size_t)dir * 64 * 512 + t;
    uint4 wreg[46];
    #pragma unroll
    for (int c = 0; c < 46; ++c) wreg[c] = gw[(size_t)c * 512];
    #pragma unroll
    for (int c = 46; c < 64; ++c) wlds[(c - 46) * 512 + t] = gw[(size_t)c * 512];
    if (t < 256) { hh16[0][t >> 7][t & 127] = 0; }
    float cst = 0.f, hst = 0.f;
    __syncthreads();
    const int khoff = kh * 512;
    #pragma unroll 1
    for (int step = 0; step < S; ++step) {
        int s = dir ? (S - 1 - step) : step;
        int cur = step & 1, nxt = cur ^ 1;
        const ushort* xp = xproj + ((size_t)(s * B + b)) * 2048 + dir * 1024 + j + khoff;
        ushort xra = xp[0], xrb = xp[256];
        float a0 = 0.f, a1 = 0.f, a2 = 0.f, a3 = 0.f;
        #pragma unroll
        for (int p = 0; p < 16; ++p) {
            uint4 hp = *(const uint4*)(&hh16[cur][kh][p * 8]);
            uint4 wi = wreg[p];
            uint4 wf = wreg[16 + p];
            uint4 wg = (p < 14) ? wreg[32 + p] : wlds[(p - 14) * 512 + t];
            uint4 wo = wlds[(p + 2) * 512 + t];
            h2f p0 = asH2(hp.x), p1 = asH2(hp.y), p2 = asH2(hp.z), p3 = asH2(hp.w);
            a0 = dot2(p0, asH2(wi.x), a0); a0 = dot2(p1, asH2(wi.y), a0);
            a0 = dot2(p2, asH2(wi.z), a0); a0 = dot2(p3, asH2(wi.w), a0);
            a1 = dot2(p0, asH2(wf.x), a1); a1 = dot2(p1, asH2(wf.y), a1);
            a1 = dot2(p2, asH2(wf.z), a1); a1 = dot2(p3, asH2(wf.w), a1);
            a2 = dot2(p0, asH2(wg.x), a2); a2 = dot2(p1, asH2(wg.y), a2);
            a2 = dot2(p2, asH2(wg.z), a2); a2 = dot2(p3, asH2(wg.w), a2);
            a3 = dot2(p0, asH2(wo.x), a3); a3 = dot2(p1, asH2(wo.y), a3);
            a3 = dot2(p2, asH2(wo.z), a3); a3 = dot2(p3, asH2(wo.w), a3);
        }
        float xv0 = (float)__builtin_bit_cast(_Float16, xra);
        float xv1 = (float)__builtin_bit_cast(_Float16, xrb);
        a0 += kh ? 0.f : xv0;  a1 += kh ? 0.f : xv1;
        a2 += kh ? xv0 : 0.f;  a3 += kh ? xv1 : 0.f;
        a0 += __shfl_xor(a0, 1); a1 += __shfl_xor(a1, 1);
        a2 += __shfl_xor(a2, 1); a3 += __shfl_xor(a3, 1);
        cst = sigmoidf_(a1) * cst + sigmoidf_(a0) * tanhf_(a2);
        hst = sigmoidf_(a3) * tanhf_(cst);
        if (kh == 0) {
            encoutB[((size_t)(b * S + s)) * 512 + dir * 256 + j] = f2bf(hst);
            hh16[nxt][j >> 7][j & 127] = __builtin_bit_cast(ushort, (_Float16)hst);
        }
        __syncthreads();
    }
    if (kh == 0) {
        hfin[(dir * 32 + b) * 256 + j] = hst;
        cfin[(dir * 32 + b) * 256 + j] = cst;
    }
}

// ---------------- decoder init ----------------
__global__ __launch_bounds__(256)
void initdec_kernel(const float* __restrict__ hfin, const float* __restrict__ cfin,
                    const float* __restrict__ wrhT, const float* __restrict__ b_rh,
                    const float* __restrict__ wrcT, const float* __restrict__ b_rc,
                    float* __restrict__ hPP, float* __restrict__ cPP, float* __restrict__ ctxPP)
{
    int b = blockIdx.x, j = threadIdx.x;
    float ah = b_rh[j], ac = b_rc[j];
    for (int k = 0; k < 512; ++k) {
        float hv = (k < 256) ? hfin[b * 256 + k] : hfin[(32 + b) * 256 + k - 256];
        float cv = (k < 256) ? cfin[b * 256 + k] : cfin[(32 + b) * 256 + k - 256];
        ah += hv * wrhT[k * 256 + j];
        ac += cv * wrcT[k * 256 + j];
    }
    hPP[b * 256 + j] = fmaxf(ah, 0.f);
    cPP[b * 256 + j] = fmaxf(ac, 0.f);
    ctxPP[b * 512 + j] = 0.f;
    ctxPP[b * 512 + 256 + j] = 0.f;
}

// ---------------- hid helper ----------------
DEV void hid_block(int idx, int tid, const float* hin, const float* cin, const float* ctxin,
                   const float* wo1T, const float* b_o1, ushort* hid_prev,
                   float xs[8][1024], float redh[4][8][64])
{
    int bg = idx >> 2, dg = idx & 3;
    for (int i = tid; i < 8192; i += 256) {
        int b8 = i >> 10, k = i & 1023;
        int b = bg * 8 + b8;
        float v;
        if (k < 256)      v = hin[b * 256 + k];
        else if (k < 512) v = cin[b * 256 + k - 256];
        else              v = ctxin[b * 512 + (k - 512)];
        xs[b8][k] = v;
    }
    __syncthreads();
    int dl = tid & 63, kq = tid >> 6;
    int d = dg * 64 + dl;
    float acc8[8] = {};
    for (int k = kq * 256; k < kq * 256 + 256; k += 4) {
        float w0 = wo1T[(size_t)k * 256 + d];
        float w1 = wo1T[(size_t)(k + 1) * 256 + d];
        float w2 = wo1T[(size_t)(k + 2) * 256 + d];
        float w3 = wo1T[(size_t)(k + 3) * 256 + d];
        #pragma unroll
        for (int b8 = 0; b8 < 8; ++b8) {
            float4 x = *(const float4*)(&xs[b8][k]);
            acc8[b8] += w0 * x.x + w1 * x.y + w2 * x.z + w3 * x.w;
        }
    }
    #pragma unroll
    for (int b8 = 0; b8 < 8; ++b8) redh[kq][b8][dl] = acc8[b8];
    __syncthreads();
    for (int i = tid; i < 512; i += 256) {
        int b8 = i >> 6, dl2 = i & 63;
        int d2 = dg * 64 + dl2;
        float v = redh[0][b8][dl2] + redh[1][b8][dl2] + redh[2][b8][dl2] + redh[3][b8][dl2] + b_o1[d2];
        hid_prev[(size_t)(bg * 8 + b8) * 256 + d2] = f2bf(v);
    }
}

// ---------------- K1: lstm (128) + hid(t-1) (16) ----------------
__global__ __launch_bounds__(256)
void dec_step1_kernel(const float* __restrict__ wcat, const float* __restrict__ bcv,
                      const float* __restrict__ ctxin,
                      const float* __restrict__ hin, const float* __restrict__ cin,
                      float* __restrict__ hout, float* __restrict__ cout,
                      const float* __restrict__ embt,
                      const float* __restrict__ wo1T, const float* __restrict__ b_o1,
                      ushort* __restrict__ hid_prev, int havePrev)
{
    __shared__ float pre[256];
    __shared__ float xs[8][1024];
    __shared__ float redh[4][8][64];
    int blk = blockIdx.x, tid = threadIdx.x;
    if (blk < 128) {
        int b = tid & 31, ci = tid >> 5;
        int gi = ci >> 1, jj = ci & 1;
        int j = (blk << 1) + jj;
        int col = gi * 256 + j;
        float acc = bcv[col];
        const float4* w = (const float4*)(wcat + (size_t)col * 896);
        const float4* x0 = (const float4*)(ctxin + b * 512);
        #pragma unroll 8
        for (int u = 0; u < 128; ++u) { float4 a = w[u], q = x0[u]; acc += a.x*q.x + a.y*q.y + a.z*q.z + a.w*q.w; }
        const float4* x1 = (const float4*)(embt + b * 128);
        #pragma unroll 8
        for (int u = 0; u < 32; ++u) { float4 a = w[128 + u], q = x1[u]; acc += a.x*q.x + a.y*q.y + a.z*q.z + a.w*q.w; }
        const float4* x2 = (const float4*)(hin + b * 256);
        #pragma unroll 8
        for (int u = 0; u < 64; ++u) { float4 a = w[160 + u], q = x2[u]; acc += a.x*q.x + a.y*q.y + a.z*q.z + a.w*q.w; }
        pre[tid] = acc;
        __syncthreads();
        if (tid < 64) {
            int b2 = tid & 31, qq = tid >> 5;
            int j2 = (blk << 1) + qq;
            float iv = pre[(0 + qq) * 32 + b2];
            float fv = pre[(2 + qq) * 32 + b2];
            float gv = pre[(4 + qq) * 32 + b2];
            float ov = pre[(6 + qq) * 32 + b2];
            float cp = cin[b2 * 256 + j2];
            float cn = sigmoidf_(fv) * cp + sigmoidf_(iv) * tanhf_(gv);
            float hn = sigmoidf_(ov) * tanhf_(cn);
            cout[b2 * 256 + j2] = cn;
            hout[b2 * 256 + j2] = hn;
        }
    } else {
        if (!havePrev) return;
        hid_block(blk - 128, tid, hin, cin, ctxin, wo1T, b_o1, hid_prev, xs, redh);
    }
}

// ---------------- tail: hid for t = T-1 ----------------
__global__ __launch_bounds__(256)
void dec_tail_kernel(const float* __restrict__ hin, const float* __restrict__ cin,
                     const float* __restrict__ ctxin,
                     const float* __restrict__ wo1T, const float* __restrict__ b_o1,
                     ushort* __restrict__ hid_prev)
{
    __shared__ float xs[8][1024];
    __shared__ float redh[4][8][64];
    hid_block(blockIdx.x, threadIdx.x, hin, cin, ctxin, wo1T, b_o1, hid_prev, xs, redh);
}

// ---------------- K3: fused per-b attention (daf, e, softmax, atts, ctx, pgen) ----------------
__global__ __launch_bounds__(512)
void dec_attn_kernel(const float* __restrict__ h, const float* __restrict__ c,
                     const ushort* __restrict__ wafbf, const float* __restrict__ b_af,
                     const ushort* __restrict__ encfeatB, const float* __restrict__ wv,
                     const int* __restrict__ inputs, const ushort* __restrict__ encoutB,
                     const float* __restrict__ ctxold, float* __restrict__ ctxnew,
                     const float* __restrict__ embt, const float* __restrict__ wz,
                     const float* __restrict__ cpgp,
                     float* __restrict__ pgen_t, float* __restrict__ atts_t)
{
    __shared__ float hc[512];
    __shared__ float dafL[512];
    __shared__ float scL[400];
    __shared__ float redn[512];
    __shared__ float part8[8][512];
    __shared__ float ctxL[512];
    int b = blockIdx.x, tid = threadIdx.x;
    int sl = tid >> 6, dth = tid & 63;
    hc[tid] = (tid < 256) ? h[b * 256 + tid] : c[b * 256 + tid - 256];
    __syncthreads();
    // P1: daf — k split across waves, d-chunks per lane via uint4 (coalesced, high MLP)
    {
        float acc8[8] = {};
        const ushort* wbase = wafbf + (size_t)(sl * 64) * 512 + dth * 8;
        #pragma unroll 8
        for (int kk = 0; kk < 64; ++kk) {
            uint4 u = *(const uint4*)(wbase + (size_t)kk * 512);
            float hk = hc[sl * 64 + kk];
            acc8[0] += hk * bf2f(u.x & 0xffffu);
            acc8[1] += hk * bf2f(u.x >> 16);
            acc8[2] += hk * bf2f(u.y & 0xffffu);
            acc8[3] += hk * bf2f(u.y >> 16);
            acc8[4] += hk * bf2f(u.z & 0xffffu);
            acc8[5] += hk * bf2f(u.z >> 16);
            acc8[6] += hk * bf2f(u.w & 0xffffu);
            acc8[7] += hk * bf2f(u.w >> 16);
        }
        #pragma unroll
        for (int jj = 0; jj < 8; ++jj) part8[sl][dth * 8 + jj] = acc8[jj];
    }
    __syncthreads();
    {
        float v = b_af[tid];
        #pragma unroll
        for (int w8 = 0; w8 < 8; ++w8) v += part8[w8][tid];
        dafL[tid] = v;
    }
    __syncthreads();
    // preload daf & wv slices into regs (avoids strided-LDS bank conflicts in s-loop)
    float dreg[8], wreg[8];
    #pragma unroll
    for (int jj = 0; jj < 8; ++jj) { dreg[jj] = dafL[dth * 8 + jj]; wreg[jj] = wv[dth * 8 + jj]; }
    // P2: e[s] -> exp (wave sl handles s = sl + 8i)
    for (int i = 0; i < 50; ++i) {
        int s = sl + i * 8;
        uint4 u = *(const uint4*)(encfeatB + ((size_t)b * S + s) * 512 + dth * 8);
        h2f e0 = asH2(u.x), e1 = asH2(u.y), e2 = asH2(u.z), e3 = asH2(u.w);
        float e = tanhf_((float)e0.x + dreg[0]) * wreg[0] + tanhf_((float)e0.y + dreg[1]) * wreg[1]
                + tanhf_((float)e1.x + dreg[2]) * wreg[2] + tanhf_((float)e1.y + dreg[3]) * wreg[3]
                + tanhf_((float)e2.x + dreg[4]) * wreg[4] + tanhf_((float)e2.y + dreg[5]) * wreg[5]
                + tanhf_((float)e3.x + dreg[6]) * wreg[6] + tanhf_((float)e3.y + dreg[7]) * wreg[7];
        e += __shfl_xor(e, 1);  e += __shfl_xor(e, 2);
        e += __shfl_xor(e, 4);  e += __shfl_xor(e, 8);
        e += __shfl_xor(e, 16); e += __shfl_xor(e, 32);
        if (dth == 0) {
            float m = (inputs[s * 32 + b] != 0) ? 1.f : 0.f;
            scL[s] = m * __expf(e);
        }
    }
    __syncthreads();
    // P3: softmax denom
    redn[tid] = (tid < 400) ? scL[tid] : 0.f;
    __syncthreads();
    for (int o = 256; o > 0; o >>= 1) { if (tid < o) redn[tid] += redn[tid + o]; __syncthreads(); }
    float rinv = 1.f / redn[0];
    if (tid < 400) atts_t[tid * 32 + b] = scL[tid] * rinv;
    __syncthreads();
    // P4: ctx partials (unnormalized; scale by rinv at reduce)
    {
        float acc8[8] = {};
        for (int i = 0; i < 50; ++i) {
            int s = sl + i * 8;
            float a = scL[s];
            uint4 u = *(const uint4*)(encoutB + ((size_t)b * S + s) * 512 + dth * 8);
            acc8[0] += a * bf2f(u.x & 0xffffu);
            acc8[1] += a * bf2f(u.x >> 16);
            acc8[2] += a * bf2f(u.y & 0xffffu);
            acc8[3] += a * bf2f(u.y >> 16);
            acc8[4] += a * bf2f(u.z & 0xffffu);
            acc8[5] += a * bf2f(u.z >> 16);
            acc8[6] += a * bf2f(u.w & 0xffffu);
            acc8[7] += a * bf2f(u.w >> 16);
        }
        #pragma unroll
        for (int jj = 0; jj < 8; ++jj) part8[sl][dth * 8 + jj] = acc8[jj];
    }
    __syncthreads();
    {
        float v = 0.f;
        #pragma unroll
        for (int s8 = 0; s8 < 8; ++s8) v += part8[s8][tid];
        v *= rinv;
        ctxL[tid] = v;
        ctxnew[(size_t)b * 512 + tid] = v;
    }
    __syncthreads();
    // P5: pgen = sigmoid(wz . [ctx_t; h; c; ctx_{t-1}; emb_t] + cpgp)
    {
        float pp = 0.f;
        for (int k = tid; k < 1664; k += 512) {
            float zv;
            if (k < 512)        zv = ctxL[k];
            else if (k < 1024)  zv = hc[k - 512];
            else if (k < 1536)  zv = ctxold[(size_t)b * 512 + (k - 1024)];
            else                zv = embt[b * 128 + (k - 1536)];
            pp += wz[k] * zv;
        }
        redn[tid] = pp;
        __syncthreads();
        for (int o = 256; o > 0; o >>= 1) { if (tid < o) redn[tid] += redn[tid + o]; __syncthreads(); }
        if (tid == 0) pgen_t[b] = sigmoidf_(redn[0] + cpgp[0]);
    }
}

// ---------------- batched out: fp8 row-sum, scale+write, scatter ----------------
__global__ __launch_bounds__(256)
void dec_out2_kernel(const unsigned char* __restrict__ pbuf, const float* __restrict__ pgenAll,
                     const int* __restrict__ tex, const float* __restrict__ attsAll,
                     float* __restrict__ outsAll)
{
    int tb = blockIdx.x, t = threadIdx.x;
    int tstep = tb >> 5, b = tb & 31;
    const unsigned char* prow = pbuf + (size_t)tb * VP;
    float part = 0.f;
    for (int i = t; i < V / 8; i += 256) {
        uint2 u = *(const uint2*)(prow + i * 8);
        unsigned w0 = u.x, w1 = u.y;
        part += e42f(w0 & 255) + e42f((w0 >> 8) & 255) + e42f((w0 >> 16) & 255) + e42f(w0 >> 24);
        part += e42f(w1 & 255) + e42f((w1 >> 8) & 255) + e42f((w1 >> 16) & 255) + e42f(w1 >> 24);
    }
    __shared__ float red[256];
    red[t] = part;
    __syncthreads();
    for (int o = 128; o > 0; o >>= 1) { if (t < o) red[t] += red[t + o]; __syncthreads(); }
    float pg = pgenAll[tb];
    float sca = pg / red[0];
    float om = 1.f - pg;
    float* orow = outsAll + (size_t)tstep * B * VO + (size_t)b * VO;
    for (int i = t; i < V / 8; i += 256) {
        uint2 u = *(const uint2*)(prow + i * 8);
        unsigned w0 = u.x, w1 = u.y;
        float2* o2 = (float2*)(orow + i * 8);
        o2[0] = make_float2(e42f(w0 & 255) * sca, e42f((w0 >> 8) & 255) * sca);
        o2[1] = make_float2(e42f((w0 >> 16) & 255) * sca, e42f(w0 >> 24) * sca);
        o2[2] = make_float2(e42f(w1 & 255) * sca, e42f((w1 >> 8) & 255) * sca);
        o2[3] = make_float2(e42f((w1 >> 16) & 255) * sca, e42f(w1 >> 24) * sca);
    }
    if (t < OOV) orow[V + t] = 0.f;
    __syncthreads();
    const float* attst = attsAll + (size_t)tstep * SB;
    for (int si = t; si < 400; si += 256)
        atomicAdd(orow + tex[si * 32 + b], om * attst[si * 32 + b]);
}

// ---------------- host ----------------
extern "C" void kernel_launch(void* const* d_in, const int* in_sizes, int n_in,
                              void* d_out, int out_size, void* d_ws, size_t ws_size,
                              hipStream_t stream)
{
    const int*   inputs  = (const int*)d_in[0];
    const int*   toksAll = (const int*)d_in[2];
    const int*   tex     = (const int*)d_in[3];
    const float* emb     = (const float*)d_in[5];
    const float* Wih_f   = (const float*)d_in[6];
    const float* Whh_f   = (const float*)d_in[7];
    const float* bih_f   = (const float*)d_in[8];
    const float* bhh_f   = (const float*)d_in[9];
    const float* Wih_b   = (const float*)d_in[10];
    const float* Whh_b   = (const float*)d_in[11];
    const float* bih_b   = (const float*)d_in[12];
    const float* bhh_b   = (const float*)d_in[13];
    const float* W_feat  = (const float*)d_in[14];
    const float* W_rh    = (const float*)d_in[15];
    const float* b_rh    = (const float*)d_in[16];
    const float* W_rc    = (const float*)d_in[17];
    const float* b_rc    = (const float*)d_in[18];
    const float* W_af    = (const float*)d_in[19];
    const float* b_af    = (const float*)d_in[20];
    const float* w_v     = (const float*)d_in[21];
    const float* W_ctx   = (const float*)d_in[22];
    const float* b_ctx   = (const float*)d_in[23];
    const float* dWih    = (const float*)d_in[24];
    const float* dWhh    = (const float*)d_in[25];
    const float* dbih    = (const float*)d_in[26];
    const float* dbhh    = (const float*)d_in[27];
    const float* W_pg    = (const float*)d_in[28];
    const float* b_pg    = (const float*)d_in[29];
    const float* W_o1    = (const float*)d_in[30];
    const float* b_o1    = (const float*)d_in[31];
    const float* W_o2    = (const float*)d_in[32];
    const float* b_o2    = (const float*)d_in[33];

    char* wsb = (char*)d_ws;
    ushort*   emb2d   = (ushort*)(wsb + OFF_EMB2D);
    ushort*   wihcat  = (ushort*)(wsb + OFF_WIHCAT);
    float*    biasx   = (float*)(wsb + OFF_BIASX);
    ushort*   wfeatbf = (ushort*)(wsb + OFF_WFEAT);
    ushort*   wo2bf   = (ushort*)(wsb + OFF_WO2);
    unsigned* whh2    = (unsigned*)(wsb + OFF_WHH2);
    float*    wcat    = (float*)(wsb + OFF_WCAT);
    float*    bcv     = (float*)(wsb + OFF_BC);
    float*    cpgp    = (float*)(wsb + OFF_CPG);
    float*    wrhT    = (float*)(wsb + OFF_WRHT);
    float*    wrcT    = (float*)(wsb + OFF_WRCT);
    float*    embdec  = (float*)(wsb + OFF_EMBDEC);
    float*    wz      = (float*)(wsb + OFF_WZ);
    ushort*   wafbf   = (ushort*)(wsb + OFF_WAFT);
    float*    wo1T    = (float*)(wsb + OFF_WO1T);
    ushort*   xproj   = (ushort*)(wsb + OFF_XPROJ);
    ushort*   encoutB = (ushort*)(wsb + OFF_ENCOUT);
    ushort*   encfeatB= (ushort*)(wsb + OFF_ENCFEAT);
    float*    hfin    = (float*)(wsb + OFF_HFIN);
    float*    cfin    = (float*)(wsb + OFF_CFIN);
    float*    hPP     = (float*)(wsb + OFF_HPP);
    float*    cPP     = (float*)(wsb + OFF_CPP);
    float*    ctxPP   = (float*)(wsb + OFF_CTXPP);
    float*    pgenAll = (float*)(wsb + OFF_PGEN);
    ushort*   hidAll  = (ushort*)(wsb + OFF_HIDALL);
    unsigned char* pbuf = (unsigned char*)(wsb + OFF_PBUF);

    float* outs = (float*)d_out;
    float* atts = outs + (size_t)T * B * VO;

    int prep_blocks = (int)((PREP_TOTAL + 255) / 256);
    prep_kernel<<<prep_blocks, 256, 0, stream>>>(
        Wih_f, Wih_b, bih_f, bhh_f, bih_b, bhh_b, W_feat, W_o2, Whh_f, Whh_b,
        dWih, W_ctx, W_pg, b_pg, b_ctx, dbih, dbhh, emb, inputs, dWhh, W_rh, W_rc,
        toksAll, W_af, W_o1,
        emb2d, wihcat, biasx, wfeatbf, wo2bf, whh2, wcat, cpgp, bcv, wrhT, wrcT,
        embdec, wz, wafbf, wo1T);

    gemm_nt<64, 64, 256, 1, true, false><<<dim3(2048 / 64, SB / 64), 256, 0, stream>>>(
        emb2d, 128, wihcat, 128, (void*)xproj, 2048, biasx, SB, 2048, 128);

    enc_kernel<<<64, 512, 0, stream>>>(xproj, (const uint4*)whh2, encoutB, hfin, cfin);

    initdec_kernel<<<32, 256, 0, stream>>>(hfin, cfin, wrhT, b_rh, wrcT, b_rc, hPP, cPP, ctxPP);

    gemm_nt<64, 64, 256, 1, false, false><<<dim3(512 / 64, SB / 64), 256, 0, stream>>>(
        encoutB, 512, wfeatbf, 512, (void*)encfeatB, 512, nullptr, SB, 512, 512);

    for (int t = 0; t < T; ++t) {
        int p = t & 1, q = p ^ 1;
        float* ctxin = ctxPP + (size_t)p * 16384;
        float* hin = hPP + (size_t)p * 8192;
        float* cin = cPP + (size_t)p * 8192;
        float* hout = hPP + (size_t)q * 8192;
        float* cout = cPP + (size_t)q * 8192;
        const float* embt = embdec + (size_t)t * 4096;
        ushort* hid_prev = (t > 0) ? hidAll + (size_t)(t - 1) * 8192 : hidAll;

        dec_step1_kernel<<<144, 256, 0, stream>>>(wcat, bcv, ctxin, hin, cin,
                                                  hout, cout, embt, wo1T, b_o1,
                                                  hid_prev, t > 0 ? 1 : 0);
        dec_attn_kernel<<<32, 512, 0, stream>>>(hout, cout, wafbf, b_af, encfeatB, w_v,
                                                inputs, encoutB,
                                                ctxin, ctxPP + (size_t)q * 16384,
                                                embt, wz, cpgp,
                                                pgenAll + (size_t)t * 32,
                                                atts + (size_t)t * SB);
    }
    // tail: hid for t = T-1 (states + ctx_{T-1} in slot 0 after t=31)
    dec_tail_kernel<<<16, 256, 0, stream>>>(hPP, cPP, ctxPP, wo1T, b_o1,
                                            hidAll + (size_t)(T - 1) * 8192);

    gemm_nt<64, 128, 512, 4, true, true><<<dim3(391, 16), 512, 0, stream>>>(
        hidAll, 256, wo2bf, 256, (void*)pbuf, VP, b_o2, T * B, V, 256);
    dec_out2_kernel<<<T * B, 256, 0, stream>>>(pbuf, pgenAll, tex, atts, outs);
}

// Round 9
// 2875.543 us; speedup vs baseline: 6.3734x; 1.4862x over previous
//
#include <hip/hip_runtime.h>

#define DEV static __device__ __forceinline__

typedef short  s16x8 __attribute__((ext_vector_type(8)));
typedef float  f32x4 __attribute__((ext_vector_type(4)));
typedef _Float16 h2f __attribute__((ext_vector_type(2)));

constexpr int S = 400, B = 32, T = 32, V = 50000, OOV = 50, E = 128, H = 256;
constexpr int VO = V + OOV, SB = S * B;
constexpr int VP = 50048;           // fp8 pbuf row stride

DEV ushort f2bf(float x) {
    union { float f; unsigned u; } a; a.f = x;
    unsigned r = (a.u + 0x7fffu + ((a.u >> 16) & 1u)) >> 16;
    return (ushort)r;
}
DEV float bf2f(unsigned b) {
    union { unsigned u; float f; } a; a.u = b << 16; return a.f;
}
DEV float sigmoidf_(float x) { return 1.0f / (1.0f + __expf(-x)); }
DEV float tanhf_(float x) { float e = __expf(2.0f * x); return 1.0f - 2.0f / (e + 1.0f); }
DEV h2f asH2(unsigned u) { union { unsigned u; h2f h; } x; x.u = u; return x.h; }

#if __has_builtin(__builtin_amdgcn_fdot2)
DEV float dot2(h2f a, h2f b, float c) { return __builtin_amdgcn_fdot2(a, b, c, false); }
#else
DEV float dot2(h2f a, h2f b, float c) { return c + (float)a.x * (float)b.x + (float)a.y * (float)b.y; }
#endif

// fp8 e4m3 manual encode/decode (positive values only: exp of logits)
DEV unsigned f2e4(float v) {
    union { float f; unsigned u; } a; a.f = v;
    unsigned u = a.u + 0x0007FFFFu + ((a.u >> 20) & 1u);
    int e = (int)((u >> 23) & 255) - 127 + 7;
    unsigned m = (u >> 20) & 7u;
    if (e <= 0) return 0u;
    if (e > 15) { e = 15; m = 6; }
    return (unsigned)((e << 3) | m);
}
DEV float e42f(unsigned b) {
    int e = (int)((b >> 3) & 15), m = (int)(b & 7);
    if (e == 0) return (float)m * 1.953125e-3f;
    union { unsigned u; float f; } a;
    a.u = ((unsigned)(e + 120) << 23) | ((unsigned)m << 20);
    return a.f;
}

// ---------------- workspace layout ----------------
constexpr size_t SZ_EMB2D  = (size_t)SB * E * 2;
constexpr size_t SZ_WIHCAT = (size_t)2048 * 128 * 2;
constexpr size_t SZ_BIASX  = 2048 * 4;
constexpr size_t SZ_WFEAT  = (size_t)512 * 512 * 2;
constexpr size_t SZ_WO2    = (size_t)V * H * 2;
constexpr size_t SZ_WHH2   = (size_t)2 * 64 * 512 * 16;
constexpr size_t SZ_WCAT   = (size_t)1024 * 896 * 4;
constexpr size_t SZ_BC     = 1024 * 4;
constexpr size_t SZ_CPG    = 256;
constexpr size_t SZ_WRHT   = (size_t)512 * 256 * 4;
constexpr size_t SZ_WRCT   = (size_t)512 * 256 * 4;
constexpr size_t SZ_EMBDEC = (size_t)T * B * E * 4;
constexpr size_t SZ_WZ     = 1664 * 4 + 256;
constexpr size_t SZ_WAFBF  = (size_t)512 * 512 * 2;
constexpr size_t SZ_WO1BF  = (size_t)256 * 1024 * 2;
constexpr size_t SZ_CTXACC = (size_t)(T + 2) * 16384 * 4;
constexpr size_t SZ_SSUM   = (size_t)(T + 2) * 32 * 4 + 256;
constexpr size_t SZ_XALL   = (size_t)T * B * 1024 * 2;
constexpr size_t SZ_EXPS   = (size_t)T * SB * 4;
constexpr size_t SZ_XPROJ  = (size_t)SB * 2048 * 2;    // aliased by fp8 pbuf later
constexpr size_t SZ_ENCOUT = (size_t)SB * 512 * 2;     // b-major bf16
constexpr size_t SZ_ENCFEAT= (size_t)SB * 512 * 2;     // b-major f16
constexpr size_t SZ_HFIN   = (size_t)2 * B * H * 4;
constexpr size_t SZ_HPP    = (size_t)2 * B * H * 4;
constexpr size_t SZ_PGEN   = (size_t)T * B * 4;
constexpr size_t SZ_HIDALL = (size_t)T * B * 256 * 2;

constexpr size_t OFF_EMB2D  = 0;
constexpr size_t OFF_WIHCAT = OFF_EMB2D  + SZ_EMB2D;
constexpr size_t OFF_BIASX  = OFF_WIHCAT + SZ_WIHCAT;
constexpr size_t OFF_WFEAT  = OFF_BIASX  + SZ_BIASX;
constexpr size_t OFF_WO2    = OFF_WFEAT  + SZ_WFEAT;
constexpr size_t OFF_WHH2   = OFF_WO2    + SZ_WO2;
constexpr size_t OFF_WCAT   = OFF_WHH2   + SZ_WHH2;
constexpr size_t OFF_BC     = OFF_WCAT   + SZ_WCAT;
constexpr size_t OFF_CPG    = OFF_BC     + SZ_BC;
constexpr size_t OFF_WRHT   = OFF_CPG    + SZ_CPG;
constexpr size_t OFF_WRCT   = OFF_WRHT   + SZ_WRHT;
constexpr size_t OFF_EMBDEC = OFF_WRCT   + SZ_WRCT;
constexpr size_t OFF_WZ     = OFF_EMBDEC + SZ_EMBDEC;
constexpr size_t OFF_WAFBF  = OFF_WZ     + SZ_WZ;
constexpr size_t OFF_WO1BF  = OFF_WAFBF  + SZ_WAFBF;
constexpr size_t OFF_CTXACC = OFF_WO1BF  + SZ_WO1BF;
constexpr size_t OFF_SSUM   = OFF_CTXACC + SZ_CTXACC;
constexpr size_t OFF_XALL   = OFF_SSUM   + SZ_SSUM;
constexpr size_t OFF_EXPS   = OFF_XALL   + SZ_XALL;
constexpr size_t OFF_XPROJ  = OFF_EXPS   + SZ_EXPS;
constexpr size_t OFF_ENCOUT = OFF_XPROJ  + SZ_XPROJ;
constexpr size_t OFF_ENCFEAT= OFF_ENCOUT + SZ_ENCOUT;
constexpr size_t OFF_HFIN   = OFF_ENCFEAT+ SZ_ENCFEAT;
constexpr size_t OFF_CFIN   = OFF_HFIN   + SZ_HFIN;
constexpr size_t OFF_HPP    = OFF_CFIN   + SZ_HFIN;
constexpr size_t OFF_CPP    = OFF_HPP    + SZ_HPP;
constexpr size_t OFF_PGEN   = OFF_CPP    + SZ_HPP;
constexpr size_t OFF_HIDALL = OFF_PGEN   + SZ_PGEN;
constexpr size_t OFF_PBUF   = OFF_XPROJ;   // xproj dead after encoder

// ---------------- prep ----------------
constexpr long P1 = 2048L*128;     // wihcat bf16
constexpr long P2 = 2048;          // biasx
constexpr long P3 = 512L*512;      // wfeat bf16
constexpr long P4 = (long)V*H;     // wo2 bf16
constexpr long P5 = 2L*64*512*4;   // whh2 dwords
constexpr long P6 = 1024L*896;     // wcat f32
constexpr long P7 = 1;             // cpg
constexpr long P8 = 1024;          // bcv
constexpr long P9 = (long)SB*E;    // emb2d
constexpr long P10 = 512L*256;     // wrhT
constexpr long P11 = 512L*256;     // wrcT
constexpr long P12 = 32L*32*128;   // embdec
constexpr long P13 = 1664;         // wz
constexpr long P14 = 512L*512;     // wafbf (bf16, [k][d])
constexpr long P15 = 256L*1024;    // wo1bf direct
constexpr long P16 = (long)(T+2)*16384; // ctxAcc zero
constexpr long P17 = (long)(T+2)*32;    // ssumAll init
constexpr long PREP_TOTAL = P1+P2+P3+P4+P5+P6+P7+P8+P9+P10+P11+P12+P13+P14+P15+P16+P17;

__global__ __launch_bounds__(256)
void prep_kernel(const float* __restrict__ Wih_f, const float* __restrict__ Wih_b,
                 const float* __restrict__ bih_f, const float* __restrict__ bhh_f,
                 const float* __restrict__ bih_b, const float* __restrict__ bhh_b,
                 const float* __restrict__ W_feat, const float* __restrict__ W_o2,
                 const float* __restrict__ Whh_f, const float* __restrict__ Whh_b,
                 const float* __restrict__ dWih, const float* __restrict__ W_ctx,
                 const float* __restrict__ W_pg, const float* __restrict__ b_pg,
                 const float* __restrict__ b_ctx, const float* __restrict__ dbih,
                 const float* __restrict__ dbhh, const float* __restrict__ emb,
                 const int* __restrict__ inputs, const float* __restrict__ dWhh,
                 const float* __restrict__ W_rh, const float* __restrict__ W_rc,
                 const int* __restrict__ toks, const float* __restrict__ W_af,
                 const float* __restrict__ W_o1,
                 ushort* __restrict__ emb2d, ushort* __restrict__ wihcat,
                 float* __restrict__ biasx, ushort* __restrict__ wfeatbf,
                 ushort* __restrict__ wo2bf, unsigned* __restrict__ whh2,
                 float* __restrict__ wcat, float* __restrict__ cpgp,
                 float* __restrict__ bcv, float* __restrict__ wrhT,
                 float* __restrict__ wrcT, float* __restrict__ embdec,
                 float* __restrict__ wz, ushort* __restrict__ wafbf,
                 ushort* __restrict__ wo1bf, float* __restrict__ ctxAcc,
                 float* __restrict__ ssumAll)
{
    long id = (long)blockIdx.x * 256 + threadIdx.x;
    if (id < P1) { int r = id >> 7, e = id & 127;
        float v = (r < 1024) ? Wih_f[r*128+e] : Wih_b[(r-1024)*128+e];
        wihcat[id] = f2bf(v); return; }
    id -= P1;
    if (id < P2) { biasx[id] = (id < 1024) ? bih_f[id]+bhh_f[id] : bih_b[id-1024]+bhh_b[id-1024]; return; }
    id -= P2;
    if (id < P3) { wfeatbf[id] = f2bf(W_feat[id]); return; }
    id -= P3;
    if (id < P4) { wo2bf[id] = f2bf(W_o2[id]); return; }
    id -= P4;
    if (id < P5) {
        int q = id & 3; long r = id >> 2;
        int t = (int)(r & 511); r >>= 9; int c = (int)(r & 63); int dir = (int)(r >> 6);
        int gate = c >> 4, p = c & 15, kh = t & 1;
        int j = t >> 1;
        int k0 = kh * 128 + p * 8 + 2 * q;
        int row = gate * 256 + j;
        const float* W = dir ? Whh_b : Whh_f;
        h2f hv; hv.x = (_Float16)W[(size_t)row*256 + k0]; hv.y = (_Float16)W[(size_t)row*256 + k0 + 1];
        whh2[id] = __builtin_bit_cast(unsigned, hv); return; }
    id -= P5;
    if (id < P6) { int col = (int)(id / 896), k = (int)(id % 896);
        if (k < 640) {
            float acc = 0.f;
            for (int e = 0; e < 128; ++e) acc += dWih[col*128+e] * W_ctx[e*640+k];
            wcat[id] = acc;
        } else wcat[id] = dWhh[(size_t)col*256 + (k - 640)];
        return; }
    id -= P6;
    if (id < P7) { float acc = b_pg[0];
        for (int e = 0; e < 128; ++e) acc += W_pg[1024+e] * b_ctx[e];
        cpgp[0] = acc; return; }
    id -= P7;
    if (id < P8) { float acc = dbih[id] + dbhh[id];
        for (int e = 0; e < 128; ++e) acc += dWih[id*128+e] * b_ctx[e];
        bcv[id] = acc; return; }
    id -= P8;
    if (id < P9) { long sb = id >> 7; int e = id & 127;
        emb2d[id] = f2bf(emb[(size_t)inputs[sb]*128 + e]); return; }
    id -= P9;
    if (id < P10) { int j = id & 255; long k = id >> 8;
        wrhT[id] = W_rh[(size_t)j * 512 + k]; return; }
    id -= P10;
    if (id < P11) { int j = id & 255; long k = id >> 8;
        wrcT[id] = W_rc[(size_t)j * 512 + k]; return; }
    id -= P11;
    if (id < P12) { long tb = id >> 7; int e = id & 127;
        embdec[id] = emb[(size_t)toks[tb]*128 + e]; return; }
    id -= P12;
    if (id < P13) {
        int k = (int)id;
        if (k < 1024) wz[k] = W_pg[k];
        else { int u = k - 1024; float acc = 0.f;
            for (int e = 0; e < 128; ++e) acc += W_pg[1024+e] * W_ctx[e*640+u];
            wz[k] = acc; }
        return; }
    id -= P13;
    if (id < P14) { int d = id & 511; long k = id >> 9;   // wafbf[k][d]
        wafbf[id] = f2bf(W_af[(size_t)d * 512 + k]); return; }
    id -= P14;
    if (id < P15) { wo1bf[id] = f2bf(W_o1[id]); return; } // direct [d][k]
    id -= P15;
    if (id < P16) { ctxAcc[id] = 0.f; return; }
    id -= P16;
    if (id < P17) { ssumAll[id] = (id < 64) ? 1.0f : 0.f; return; }
}

// ---------------- generic bf16 MFMA GEMM ----------------
// MODE: 0 f32, 1 f16, 2 f32 exp, 3 bf16, 4 fp8 exp
template<int BM, int BN, int NT, int MODE, bool BIAS, bool SWZ>
__global__ __launch_bounds__(NT)
void gemm_nt(const ushort* __restrict__ A, int lda, const ushort* __restrict__ Bm, int ldb,
             void* __restrict__ Cp, int ldc, const float* __restrict__ bias,
             int M, int N, int K)
{
    constexpr int WN = BN / 32;
    __shared__ ushort sA[BM * 32];
    __shared__ ushort sB[BN * 32];
    int tid = threadIdx.x, lane = tid & 63, wid = tid >> 6;
    int wm = wid / WN, wn = wid % WN;
    int mb = blockIdx.y, nb = blockIdx.x;
    if (SWZ) {
        int n = gridDim.x, x = nb & 7, y = nb >> 3, q = n >> 3, r = n & 7;
        nb = (x < r ? x * (q + 1) : r * (q + 1) + (x - r) * q) + y;
    }
    int l15 = lane & 15, lg = lane >> 4;
    f32x4 acc[2][2] = {};
    for (int k0 = 0; k0 < K; k0 += 32) {
        for (int idx = tid; idx < BM * 4; idx += NT) {
            int r = idx >> 2, kc = (idx & 3) << 3;
            int row = mb * BM + r;
            uint4 v = make_uint4(0u, 0u, 0u, 0u);
            if (row < M) v = *(const uint4*)(A + (size_t)row * lda + k0 + kc);
            *(uint4*)(&sA[r * 32 + kc]) = v;
        }
        for (int idx = tid; idx < BN * 4; idx += NT) {
            int r = idx >> 2, kc = (idx & 3) << 3;
            int row = nb * BN + r;
            uint4 v = make_uint4(0u, 0u, 0u, 0u);
            if (row < N) v = *(const uint4*)(Bm + (size_t)row * ldb + k0 + kc);
            *(uint4*)(&sB[r * 32 + kc]) = v;
        }
        __syncthreads();
        s16x8 a0 = *(const s16x8*)(&sA[(wm * 32 + l15) * 32 + lg * 8]);
        s16x8 a1 = *(const s16x8*)(&sA[(wm * 32 + 16 + l15) * 32 + lg * 8]);
        s16x8 b0 = *(const s16x8*)(&sB[(wn * 32 + l15) * 32 + lg * 8]);
        s16x8 b1 = *(const s16x8*)(&sB[(wn * 32 + 16 + l15) * 32 + lg * 8]);
        acc[0][0] = __builtin_amdgcn_mfma_f32_16x16x32_bf16(a0, b0, acc[0][0], 0, 0, 0);
        acc[0][1] = __builtin_amdgcn_mfma_f32_16x16x32_bf16(a0, b1, acc[0][1], 0, 0, 0);
        acc[1][0] = __builtin_amdgcn_mfma_f32_16x16x32_bf16(a1, b0, acc[1][0], 0, 0, 0);
        acc[1][1] = __builtin_amdgcn_mfma_f32_16x16x32_bf16(a1, b1, acc[1][1], 0, 0, 0);
        __syncthreads();
    }
    int cb = nb * BN + wn * 32, rb = mb * BM + wm * 32;
    #pragma unroll
    for (int mf = 0; mf < 2; ++mf)
    #pragma unroll
    for (int nf = 0; nf < 2; ++nf) {
        int col = cb + nf * 16 + l15;
        float bv = 0.f;
        if (BIAS) { if (col < N) bv = bias[col]; }
        #pragma unroll
        for (int r = 0; r < 4; ++r) {
            int row = rb + mf * 16 + lg * 4 + r;
            if (row < M && col < N) {
                float v = acc[mf][nf][r] + bv;
                if (MODE == 0)      ((float*)Cp)[(size_t)row * ldc + col] = v;
                else if (MODE == 1) ((ushort*)Cp)[(size_t)row * ldc + col] = __builtin_bit_cast(ushort, (_Float16)v);
                else if (MODE == 2) ((float*)Cp)[(size_t)row * ldc + col] = __expf(v);
                else if (MODE == 3) ((ushort*)Cp)[(size_t)row * ldc + col] = f2bf(v);
                else                ((unsigned char*)Cp)[(size_t)row * ldc + col] = (unsigned char)f2e4(__expf(v));
            }
        }
    }
}

// ---------------- encoder (bank-padded) ----------------
__global__ __launch_bounds__(512, 2)
void enc_kernel(const ushort* __restrict__ xproj, const uint4* __restrict__ whh2,
                ushort* __restrict__ encoutB, float* __restrict__ hfin, float* __restrict__ cfin)
{
    __shared__ uint4  wlds[18 * 512];
    __shared__ __attribute__((aligned(16))) ushort hh16[2][2][136];
    int b = blockIdx.x & 31, dir = blockIdx.x >> 5;
    int t = threadIdx.x, j = t >> 1, kh = t & 1;
    const uint4* gw = whh2 + (size_t)dir * 64 * 512 + t;
    uint4 wreg[46];
    #pragma unroll
    for (int c = 0; c < 46; ++c) wreg[c] = gw[(size_t)c * 512];
    #pragma unroll
    for (int c = 46; c < 64; ++c) wlds[(c - 46) * 512 + t] = gw[(size_t)c * 512];
    if (t < 256) { hh16[0][t >> 7][t & 127] = 0; }
    float cst = 0.f, hst = 0.f;
    __syncthreads();
    const int khoff = kh * 512;
    #pragma unroll 1
    for (int step = 0; step < S; ++step) {
        int s = dir ? (S - 1 - step) : step;
        int cur = step & 1, nxt = cur ^ 1;
        const ushort* xp = xproj + ((size_t)(s * B + b)) * 2048 + dir * 1024 + j + khoff;
        ushort xra = xp[0], xrb = xp[256];
        float a0 = 0.f, a1 = 0.f, a2 = 0.f, a3 = 0.f;
        #pragma unroll
        for (int p = 0; p < 16; ++p) {
            uint4 hp = *(const uint4*)(&hh16[cur][kh][p * 8]);
            uint4 wi = wreg[p];
            uint4 wf = wreg[16 + p];
            uint4 wg = (p < 14) ? wreg[32 + p] : wlds[(p - 14) * 512 + t];
            uint4 wo = wlds[(p + 2) * 512 + t];
            h2f p0 = asH2(hp.x), p1 = asH2(hp.y), p2 = asH2(hp.z), p3 = asH2(hp.w);
            a0 = dot2(p0, asH2(wi.x), a0); a0 = dot2(p1, asH2(wi.y), a0);
            a0 = dot2(p2, asH2(wi.z), a0); a0 = dot2(p3, asH2(wi.w), a0);
            a1 = dot2(p0, asH2(wf.x), a1); a1 = dot2(p1, asH2(wf.y), a1);
            a1 = dot2(p2, asH2(wf.z), a1); a1 = dot2(p3, asH2(wf.w), a1);
            a2 = dot2(p0, asH2(wg.x), a2); a2 = dot2(p1, asH2(wg.y), a2);
            a2 = dot2(p2, asH2(wg.z), a2); a2 = dot2(p3, asH2(wg.w), a2);
            a3 = dot2(p0, asH2(wo.x), a3); a3 = dot2(p1, asH2(wo.y), a3);
            a3 = dot2(p2, asH2(wo.z), a3); a3 = dot2(p3, asH2(wo.w), a3);
        }
        float xv0 = (float)__builtin_bit_cast(_Float16, xra);
        float xv1 = (float)__builtin_bit_cast(_Float16, xrb);
        a0 += kh ? 0.f : xv0;  a1 += kh ? 0.f : xv1;
        a2 += kh ? xv0 : 0.f;  a3 += kh ? xv1 : 0.f;
        a0 += __shfl_xor(a0, 1); a1 += __shfl_xor(a1, 1);
        a2 += __shfl_xor(a2, 1); a3 += __shfl_xor(a3, 1);
        cst = sigmoidf_(a1) * cst + sigmoidf_(a0) * tanhf_(a2);
        hst = sigmoidf_(a3) * tanhf_(cst);
        if (kh == 0) {
            encoutB[((size_t)(b * S + s)) * 512 + dir * 256 + j] = f2bf(hst);
            hh16[nxt][j >> 7][j & 127] = __builtin_bit_cast(ushort, (_Float16)hst);
        }
        __syncthreads();
    }
    if (kh == 0) {
        hfin[(dir * 32 + b) * 256 + j] = hst;
        cfin[(dir * 32 + b) * 256 + j] = cst;
    }
}

// ---------------- decoder init ----------------
__global__ __launch_bounds__(256)
void initdec_kernel(const float* __restrict__ hfin, const float* __restrict__ cfin,
                    const float* __restrict__ wrhT, const float* __restrict__ b_rh,
                    const float* __restrict__ wrcT, const float* __restrict__ b_rc,
                    float* __restrict__ hPP, float* __restrict__ cPP)
{
    int b = blockIdx.x, j = threadIdx.x;
    float ah = b_rh[j], ac = b_rc[j];
    for (int k = 0; k < 512; ++k) {
        float hv = (k < 256) ? hfin[b * 256 + k] : hfin[(32 + b) * 256 + k - 256];
        float cv = (k < 256) ? cfin[b * 256 + k] : cfin[(32 + b) * 256 + k - 256];
        ah += hv * wrhT[k * 256 + j];
        ac += cv * wrcT[k * 256 + j];
    }
    hPP[b * 256 + j] = fmaxf(ah, 0.f);
    cPP[b * 256 + j] = fmaxf(ac, 0.f);
}

// ---------------- K1: lstm only (128 blocks) ----------------
__global__ __launch_bounds__(256)
void dec_lstm2_kernel(const float* __restrict__ wcat, const float* __restrict__ bcv,
                      const float* __restrict__ ctxPrevAcc, const float* __restrict__ ssumPrev,
                      const float* __restrict__ hin, const float* __restrict__ cin,
                      float* __restrict__ hout, float* __restrict__ cout,
                      const float* __restrict__ embt, ushort* __restrict__ xAll_t)
{
    __shared__ float pre[256];
    int blk = blockIdx.x, tid = threadIdx.x;
    int b = tid & 31, ci = tid >> 5;
    int gi = ci >> 1, jj = ci & 1;
    int j = (blk << 1) + jj;
    int col = gi * 256 + j;
    float rinvb = 1.0f / ssumPrev[b];
    float acc = bcv[col], accC = 0.f;
    const float4* w = (const float4*)(wcat + (size_t)col * 896);
    const float4* x0 = (const float4*)(ctxPrevAcc + b * 512);
    #pragma unroll 8
    for (int u = 0; u < 128; ++u) { float4 a = w[u], q = x0[u]; accC += a.x*q.x + a.y*q.y + a.z*q.z + a.w*q.w; }
    const float4* x1 = (const float4*)(embt + b * 128);
    #pragma unroll 8
    for (int u = 0; u < 32; ++u) { float4 a = w[128 + u], q = x1[u]; acc += a.x*q.x + a.y*q.y + a.z*q.z + a.w*q.w; }
    const float4* x2 = (const float4*)(hin + b * 256);
    #pragma unroll 8
    for (int u = 0; u < 64; ++u) { float4 a = w[160 + u], q = x2[u]; acc += a.x*q.x + a.y*q.y + a.z*q.z + a.w*q.w; }
    pre[tid] = acc + rinvb * accC;
    __syncthreads();
    if (tid < 64) {
        int b2 = tid & 31, qq = tid >> 5;
        int j2 = (blk << 1) + qq;
        float iv = pre[(0 + qq) * 32 + b2];
        float fv = pre[(2 + qq) * 32 + b2];
        float gv = pre[(4 + qq) * 32 + b2];
        float ov = pre[(6 + qq) * 32 + b2];
        float cp = cin[b2 * 256 + j2];
        float cn = sigmoidf_(fv) * cp + sigmoidf_(iv) * tanhf_(gv);
        float hn = sigmoidf_(ov) * tanhf_(cn);
        cout[b2 * 256 + j2] = cn;
        hout[b2 * 256 + j2] = hn;
        xAll_t[(size_t)b2 * 1024 + j2] = f2bf(hn);
        xAll_t[(size_t)b2 * 1024 + 256 + j2] = f2bf(cn);
    }
}

// ---------------- K2: attention chunk (256 blocks: b x 8 s-chunks of 50) ----------------
__global__ __launch_bounds__(512)
void dec_attn2_kernel(const float* __restrict__ h, const float* __restrict__ c,
                      const ushort* __restrict__ wafbf, const float* __restrict__ b_af,
                      const ushort* __restrict__ encfeatB, const float* __restrict__ wv,
                      const int* __restrict__ inputs, const ushort* __restrict__ encoutB,
                      float* __restrict__ expsT, float* __restrict__ ssumT,
                      float* __restrict__ ctxAccT)
{
    __shared__ float hc[512];
    __shared__ float dafL[512];
    __shared__ float scL[50];
    __shared__ float part8[8][512];
    int blk = blockIdx.x, tid = threadIdx.x;
    int b = blk >> 3, sc = blk & 7, s0 = sc * 50;
    int sl = tid >> 6, dth = tid & 63;
    hc[tid] = (tid < 256) ? h[b * 256 + tid] : c[b * 256 + tid - 256];
    __syncthreads();
    // daf: k-split across waves, d-chunks per lane (coalesced uint4, high MLP)
    {
        float acc8[8] = {};
        const ushort* wbase = wafbf + (size_t)(sl * 64) * 512 + dth * 8;
        #pragma unroll 8
        for (int kk = 0; kk < 64; ++kk) {
            uint4 u = *(const uint4*)(wbase + (size_t)kk * 512);
            float hk = hc[sl * 64 + kk];
            acc8[0] += hk * bf2f(u.x & 0xffffu);
            acc8[1] += hk * bf2f(u.x >> 16);
            acc8[2] += hk * bf2f(u.y & 0xffffu);
            acc8[3] += hk * bf2f(u.y >> 16);
            acc8[4] += hk * bf2f(u.z & 0xffffu);
            acc8[5] += hk * bf2f(u.z >> 16);
            acc8[6] += hk * bf2f(u.w & 0xffffu);
            acc8[7] += hk * bf2f(u.w >> 16);
        }
        #pragma unroll
        for (int jj = 0; jj < 8; ++jj) part8[sl][dth * 8 + jj] = acc8[jj];
    }
    __syncthreads();
    {
        float v = b_af[tid];
        #pragma unroll
        for (int w8 = 0; w8 < 8; ++w8) v += part8[w8][tid];
        dafL[tid] = v;
    }
    __syncthreads();
    float dreg[8], wreg[8];
    #pragma unroll
    for (int jj = 0; jj < 8; ++jj) { dreg[jj] = dafL[dth * 8 + jj]; wreg[jj] = wv[dth * 8 + jj]; }
    // e -> exp for this chunk's 50 rows
    for (int i = sl; i < 50; i += 8) {
        int s = s0 + i;
        uint4 u = *(const uint4*)(encfeatB + ((size_t)b * S + s) * 512 + dth * 8);
        h2f e0 = asH2(u.x), e1 = asH2(u.y), e2 = asH2(u.z), e3 = asH2(u.w);
        float e = tanhf_((float)e0.x + dreg[0]) * wreg[0] + tanhf_((float)e0.y + dreg[1]) * wreg[1]
                + tanhf_((float)e1.x + dreg[2]) * wreg[2] + tanhf_((float)e1.y + dreg[3]) * wreg[3]
                + tanhf_((float)e2.x + dreg[4]) * wreg[4] + tanhf_((float)e2.y + dreg[5]) * wreg[5]
                + tanhf_((float)e3.x + dreg[6]) * wreg[6] + tanhf_((float)e3.y + dreg[7]) * wreg[7];
        e += __shfl_xor(e, 1);  e += __shfl_xor(e, 2);
        e += __shfl_xor(e, 4);  e += __shfl_xor(e, 8);
        e += __shfl_xor(e, 16); e += __shfl_xor(e, 32);
        if (dth == 0) {
            float m = (inputs[s * 32 + b] != 0) ? 1.f : 0.f;
            float val = m * __expf(e);
            scL[i] = val;
            expsT[s * 32 + b] = val;
        }
    }
    __syncthreads();
    if (tid == 0) {
        float ss = 0.f;
        for (int i = 0; i < 50; ++i) ss += scL[i];
        atomicAdd(&ssumT[b], ss);
    }
    // ctx partial (unnormalized) -> atomic accumulate
    {
        float acc8[8] = {};
        for (int i = sl; i < 50; i += 8) {
            float a = scL[i];
            uint4 u = *(const uint4*)(encoutB + ((size_t)b * S + s0 + i) * 512 + dth * 8);
            acc8[0] += a * bf2f(u.x & 0xffffu);
            acc8[1] += a * bf2f(u.x >> 16);
            acc8[2] += a * bf2f(u.y & 0xffffu);
            acc8[3] += a * bf2f(u.y >> 16);
            acc8[4] += a * bf2f(u.z & 0xffffu);
            acc8[5] += a * bf2f(u.z >> 16);
            acc8[6] += a * bf2f(u.w & 0xffffu);
            acc8[7] += a * bf2f(u.w >> 16);
        }
        #pragma unroll
        for (int jj = 0; jj < 8; ++jj) part8[sl][dth * 8 + jj] = acc8[jj];
    }
    __syncthreads();
    {
        float v = 0.f;
        #pragma unroll
        for (int s8 = 0; s8 < 8; ++s8) v += part8[s8][tid];
        atomicAdd(&ctxAccT[b * 512 + tid], v);
    }
}

// ---------------- post-loop: materialize ctx into xAll (bf16) ----------------
__global__ __launch_bounds__(256)
void cvt_kernel(const float* __restrict__ ctxAcc, const float* __restrict__ ssumAll,
                ushort* __restrict__ xAll)
{
    int id = blockIdx.x * 256 + threadIdx.x;   // T*B*512 = 524288
    int t = id >> 14, rem = id & 16383;
    int b = rem >> 9, k = rem & 511;
    float v = ctxAcc[(size_t)(2 + t) * 16384 + rem] / ssumAll[(2 + t) * 32 + b];
    xAll[(size_t)(t * 32 + b) * 1024 + 512 + k] = f2bf(v);
}

// ---------------- post-loop: batched pgen (T*B rows) ----------------
__global__ __launch_bounds__(256)
void pgen_kernel(const ushort* __restrict__ xAll, const float* __restrict__ ctxAcc,
                 const float* __restrict__ ssumAll, const float* __restrict__ embdec,
                 const float* __restrict__ wz, const float* __restrict__ cpgp,
                 float* __restrict__ pgenAll)
{
    int row = blockIdx.x * 8 + (threadIdx.x >> 5);   // 128 blocks
    int sub = threadIdx.x & 31;
    int t = row >> 5, b = row & 31;
    float rT = 1.0f / ssumAll[(2 + t) * 32 + b];
    float rP = 1.0f / ssumAll[(1 + t) * 32 + b];
    const float* cT = ctxAcc + (size_t)(2 + t) * 16384 + b * 512;
    const float* cP = ctxAcc + (size_t)(1 + t) * 16384 + b * 512;
    const ushort* hx = xAll + (size_t)row * 1024;
    const float* em = embdec + (size_t)row * 128;
    float acc = 0.f;
    for (int k = sub; k < 1664; k += 32) {
        float zv;
        if (k < 512)        zv = cT[k] * rT;
        else if (k < 1024)  zv = bf2f(hx[k - 512]);
        else if (k < 1536)  zv = cP[k - 1024] * rP;
        else                zv = em[k - 1536];
        acc += wz[k] * zv;
    }
    acc += __shfl_xor(acc, 1); acc += __shfl_xor(acc, 2);
    acc += __shfl_xor(acc, 4); acc += __shfl_xor(acc, 8);
    acc += __shfl_xor(acc, 16);
    if (sub == 0) pgenAll[row] = sigmoidf_(acc + cpgp[0]);
}

// ---------------- batched out: fp8 row-sum, scale+write, atts-normalize, scatter ----------------
__global__ __launch_bounds__(256)
void dec_out3_kernel(const unsigned char* __restrict__ pbuf, const float* __restrict__ pgenAll,
                     const int* __restrict__ tex, const float* __restrict__ expsAll,
                     const float* __restrict__ ssumAll,
                     float* __restrict__ outsAll, float* __restrict__ attsAll)
{
    int tb = blockIdx.x, t = threadIdx.x;
    int tstep = tb >> 5, b = tb & 31;
    const unsigned char* prow = pbuf + (size_t)tb * VP;
    float part = 0.f;
    for (int i = t; i < V / 8; i += 256) {
        uint2 u = *(const uint2*)(prow + i * 8);
        unsigned w0 = u.x, w1 = u.y;
        part += e42f(w0 & 255) + e42f((w0 >> 8) & 255) + e42f((w0 >> 16) & 255) + e42f(w0 >> 24);
        part += e42f(w1 & 255) + e42f((w1 >> 8) & 255) + e42f((w1 >> 16) & 255) + e42f(w1 >> 24);
    }
    __shared__ float red[256];
    red[t] = part;
    __syncthreads();
    for (int o = 128; o > 0; o >>= 1) { if (t < o) red[t] += red[t + o]; __syncthreads(); }
    float pg = pgenAll[tb];
    float sca = pg / red[0];
    float om = 1.f - pg;
    float rinv = 1.0f / ssumAll[(2 + tstep) * 32 + b];
    float* orow = outsAll + (size_t)tstep * B * VO + (size_t)b * VO;
    for (int i = t; i < V / 8; i += 256) {
        uint2 u = *(const uint2*)(prow + i * 8);
        unsigned w0 = u.x, w1 = u.y;
        float2* o2 = (float2*)(orow + i * 8);
        o2[0] = make_float2(e42f(w0 & 255) * sca, e42f((w0 >> 8) & 255) * sca);
        o2[1] = make_float2(e42f((w0 >> 16) & 255) * sca, e42f(w0 >> 24) * sca);
        o2[2] = make_float2(e42f(w1 & 255) * sca, e42f((w1 >> 8) & 255) * sca);
        o2[3] = make_float2(e42f((w1 >> 16) & 255) * sca, e42f(w1 >> 24) * sca);
    }
    if (t < OOV) orow[V + t] = 0.f;
    __syncthreads();
    const float* expst = expsAll + (size_t)tstep * SB;
    float* attst = attsAll + (size_t)tstep * SB;
    for (int si = t; si < 400; si += 256) {
        float an = expst[si * 32 + b] * rinv;
        attst[si * 32 + b] = an;
        atomicAdd(orow + tex[si * 32 + b], om * an);
    }
}

// ---------------- host ----------------
extern "C" void kernel_launch(void* const* d_in, const int* in_sizes, int n_in,
                              void* d_out, int out_size, void* d_ws, size_t ws_size,
                              hipStream_t stream)
{
    const int*   inputs  = (const int*)d_in[0];
    const int*   toksAll = (const int*)d_in[2];
    const int*   tex     = (const int*)d_in[3];
    const float* emb     = (const float*)d_in[5];
    const float* Wih_f   = (const float*)d_in[6];
    const float* Whh_f   = (const float*)d_in[7];
    const float* bih_f   = (const float*)d_in[8];
    const float* bhh_f   = (const float*)d_in[9];
    const float* Wih_b   = (const float*)d_in[10];
    const float* Whh_b   = (const float*)d_in[11];
    const float* bih_b   = (const float*)d_in[12];
    const float* bhh_b   = (const float*)d_in[13];
    const float* W_feat  = (const float*)d_in[14];
    const float* W_rh    = (const float*)d_in[15];
    const float* b_rh    = (const float*)d_in[16];
    const float* W_rc    = (const float*)d_in[17];
    const float* b_rc    = (const float*)d_in[18];
    const float* W_af    = (const float*)d_in[19];
    const float* b_af    = (const float*)d_in[20];
    const float* w_v     = (const float*)d_in[21];
    const float* W_ctx   = (const float*)d_in[22];
    const float* b_ctx   = (const float*)d_in[23];
    const float* dWih    = (const float*)d_in[24];
    const float* dWhh    = (const float*)d_in[25];
    const float* dbih    = (const float*)d_in[26];
    const float* dbhh    = (const float*)d_in[27];
    const float* W_pg    = (const float*)d_in[28];
    const float* b_pg    = (const float*)d_in[29];
    const float* W_o1    = (const float*)d_in[30];
    const float* b_o1    = (const float*)d_in[31];
    const float* W_o2    = (const float*)d_in[32];
    const float* b_o2    = (const float*)d_in[33];

    char* wsb = (char*)d_ws;
    ushort*   emb2d   = (ushort*)(wsb + OFF_EMB2D);
    ushort*   wihcat  = (ushort*)(wsb + OFF_WIHCAT);
    float*    biasx   = (float*)(wsb + OFF_BIASX);
    ushort*   wfeatbf = (ushort*)(wsb + OFF_WFEAT);
    ushort*   wo2bf   = (ushort*)(wsb + OFF_WO2);
    unsigned* whh2    = (unsigned*)(wsb + OFF_WHH2);
    float*    wcat    = (float*)(wsb + OFF_WCAT);
    float*    bcv     = (float*)(wsb + OFF_BC);
    float*    cpgp    = (float*)(wsb + OFF_CPG);
    float*    wrhT    = (float*)(wsb + OFF_WRHT);
    float*    wrcT    = (float*)(wsb + OFF_WRCT);
    float*    embdec  = (float*)(wsb + OFF_EMBDEC);
    float*    wz      = (float*)(wsb + OFF_WZ);
    ushort*   wafbf   = (ushort*)(wsb + OFF_WAFBF);
    ushort*   wo1bf   = (ushort*)(wsb + OFF_WO1BF);
    float*    ctxAcc  = (float*)(wsb + OFF_CTXACC);
    float*    ssumAll = (float*)(wsb + OFF_SSUM);
    ushort*   xAll    = (ushort*)(wsb + OFF_XALL);
    float*    expsAll = (float*)(wsb + OFF_EXPS);
    ushort*   xproj   = (ushort*)(wsb + OFF_XPROJ);
    ushort*   encoutB = (ushort*)(wsb + OFF_ENCOUT);
    ushort*   encfeatB= (ushort*)(wsb + OFF_ENCFEAT);
    float*    hfin    = (float*)(wsb + OFF_HFIN);
    float*    cfin    = (float*)(wsb + OFF_CFIN);
    float*    hPP     = (float*)(wsb + OFF_HPP);
    float*    cPP     = (float*)(wsb + OFF_CPP);
    float*    pgenAll = (float*)(wsb + OFF_PGEN);
    ushort*   hidAll  = (ushort*)(wsb + OFF_HIDALL);
    unsigned char* pbuf = (unsigned char*)(wsb + OFF_PBUF);

    float* outs = (float*)d_out;
    float* atts = outs + (size_t)T * B * VO;

    int prep_blocks = (int)((PREP_TOTAL + 255) / 256);
    prep_kernel<<<prep_blocks, 256, 0, stream>>>(
        Wih_f, Wih_b, bih_f, bhh_f, bih_b, bhh_b, W_feat, W_o2, Whh_f, Whh_b,
        dWih, W_ctx, W_pg, b_pg, b_ctx, dbih, dbhh, emb, inputs, dWhh, W_rh, W_rc,
        toksAll, W_af, W_o1,
        emb2d, wihcat, biasx, wfeatbf, wo2bf, whh2, wcat, cpgp, bcv, wrhT, wrcT,
        embdec, wz, wafbf, wo1bf, ctxAcc, ssumAll);

    gemm_nt<64, 64, 256, 1, true, false><<<dim3(2048 / 64, SB / 64), 256, 0, stream>>>(
        emb2d, 128, wihcat, 128, (void*)xproj, 2048, biasx, SB, 2048, 128);

    enc_kernel<<<64, 512, 0, stream>>>(xproj, (const uint4*)whh2, encoutB, hfin, cfin);

    initdec_kernel<<<32, 256, 0, stream>>>(hfin, cfin, wrhT, b_rh, wrcT, b_rc, hPP, cPP);

    gemm_nt<64, 64, 256, 1, false, false><<<dim3(512 / 64, SB / 64), 256, 0, stream>>>(
        encoutB, 512, wfeatbf, 512, (void*)encfeatB, 512, nullptr, SB, 512, 512);

    for (int t = 0; t < T; ++t) {
        int p = t & 1, q = p ^ 1;
        float* hin = hPP + (size_t)p * 8192;
        float* cin = cPP + (size_t)p * 8192;
        float* hout = hPP + (size_t)q * 8192;
        float* cout = cPP + (size_t)q * 8192;
        dec_lstm2_kernel<<<128, 256, 0, stream>>>(
            wcat, bcv,
            ctxAcc + (size_t)(t + 1) * 16384, ssumAll + (t + 1) * 32,
            hin, cin, hout, cout,
            embdec + (size_t)t * 4096, xAll + (size_t)t * 32768);
        dec_attn2_kernel<<<256, 512, 0, stream>>>(
            hout, cout, wafbf, b_af, encfeatB, w_v, inputs, encoutB,
            expsAll + (size_t)t * SB, ssumAll + (2 + t) * 32,
            ctxAcc + (size_t)(2 + t) * 16384);
    }
    // materialize ctx into xAll, then batched pgen / hid GEMM / vocab GEMM / out
    cvt_kernel<<<(T * B * 512) / 256, 256, 0, stream>>>(ctxAcc, ssumAll, xAll);
    pgen_kernel<<<128, 256, 0, stream>>>(xAll, ctxAcc, ssumAll, embdec, wz, cpgp, pgenAll);
    gemm_nt<64, 64, 256, 3, true, false><<<dim3(256 / 64, 1024 / 64), 256, 0, stream>>>(
        xAll, 1024, wo1bf, 1024, (void*)hidAll, 256, b_o1, T * B, 256, 1024);
    gemm_nt<64, 128, 512, 4, true, true><<<dim3(391, 16), 512, 0, stream>>>(
        hidAll, 256, wo2bf, 256, (void*)pbuf, VP, b_o2, T * B, V, 256);
    dec_out3_kernel<<<T * B, 256, 0, stream>>>(pbuf, pgenAll, tex, expsAll, ssumAll, outs, atts);
}